// Round 3
// baseline (914.977 us; speedup 1.0000x reference)
//
#include <hip/hip_runtime.h>
#include <hip/hip_bf16.h>
#include <cstdint>
#include <cstddef>

#define DEV __device__ __forceinline__

typedef __attribute__((ext_vector_type(8))) short short8;
typedef __attribute__((ext_vector_type(4))) float f32x4;
typedef __attribute__((ext_vector_type(16))) float f32x16;

constexpr int Dm  = 256;
constexpr int Qn  = 128;
constexpr int Cn  = 512;
constexpr int Bn  = 4;

DEV unsigned short f2bf(float f){
  unsigned int u = __builtin_bit_cast(unsigned int, f);
  u += 0x7fffu + ((u >> 16) & 1u);
  return (unsigned short)(u >> 16);
}

DEV float bfhi2f(unsigned int hi){ return __builtin_bit_cast(float, hi & 0xffff0000u); }
DEV float bflo2f(unsigned int lo){ return __builtin_bit_cast(float, lo << 16); }

DEV f32x4 mfma16(short8 a, short8 b, f32x4 c){
  return __builtin_amdgcn_mfma_f32_16x16x32_bf16(a, b, c, 0, 0, 0);
}
DEV f32x16 mfma32(short8 a, short8 b, f32x16 c){
  return __builtin_amdgcn_mfma_f32_32x32x16_bf16(a, b, c, 0, 0, 0);
}

// 16x16x32 fragment load from XOR-swizzled LDS tile (rowbytes bytes/row)
DEV short8 ldfrag(const unsigned short* buf, int rowbytes, int row0, int ks, int l){
  int r = row0 + (l & 15);
  int byte = (ks * 64 + ((l >> 4) * 16)) ^ ((r & 7) << 4);
  return *(const short8*)((const char*)buf + r * rowbytes + byte);
}

// 32x32x16 A-fragment load from XOR-swizzled LDS tile (512B rows)
DEV short8 ldfrag32(const unsigned short* buf, int row0, int kc, int l){
  int r = row0 + (l & 31);
  int byte = (kc * 32 + ((l >> 5) * 16)) ^ ((r & 7) << 4);
  return *(const short8*)((const char*)buf + r * 512 + byte);
}

// async global->LDS, 16 bytes per lane; LDS dest = uniform base + lane*16
DEV void gload_lds16(const void* g, void* lds){
  __builtin_amdgcn_global_load_lds(
      (const __attribute__((address_space(1))) unsigned int*)g,
      (__attribute__((address_space(3))) unsigned int*)lds, 16, 0, 0);
}

// ---------------------------------------------------------------- converts
__global__ __launch_bounds__(256) void conv_lin_kernel(
    const float* s0, unsigned short* d0,   // in_proj 196608
    const float* s1, unsigned short* d1,   // attn_out 65536
    const float* s2, unsigned short* d2,   // o_w 65536
    const float* s3, unsigned short* d3,   // ff1 262144
    const float* s4, unsigned short* d4,   // ff2 262144
    const float* s5, unsigned short* d5,   // memory 524288
    const float* s6, unsigned short* d6)   // v_w 65536
{
  const int total = 196608 + 65536 + 65536 + 262144 + 262144 + 524288 + 65536;
  for (int i = blockIdx.x * 256 + threadIdx.x; i < total; i += gridDim.x * 256){
    int j = i;
    if (j < 196608){ d0[j] = f2bf(s0[j]); continue; } j -= 196608;
    if (j < 65536) { d1[j] = f2bf(s1[j]); continue; } j -= 65536;
    if (j < 65536) { d2[j] = f2bf(s2[j]); continue; } j -= 65536;
    if (j < 262144){ d3[j] = f2bf(s3[j]); continue; } j -= 262144;
    if (j < 262144){ d4[j] = f2bf(s4[j]); continue; } j -= 262144;
    if (j < 524288){ d5[j] = f2bf(s5[j]); continue; } j -= 524288;
    d6[j] = f2bf(s6[j]);
  }
}

// pack weight W[f][d] (256x256) into fragment order:
// out[(d>>3)*2048 + f*8 + (d&7)]  => a 32x32x16 B-frag load is 2x512B contiguous
__global__ __launch_bounds__(256) void conv_pk_kernel(
    const float* s0, unsigned short* d0,
    const float* s1, unsigned short* d1,
    const float* s2, unsigned short* d2)
{
  for (int i = blockIdx.x * 256 + threadIdx.x; i < 3 * 65536; i += gridDim.x * 256){
    int j = i & 65535; int w = i >> 16;
    int f = j >> 8, d = j & 255;
    int dj = (d >> 3) * 2048 + f * 8 + (d & 7);
    const float* s = (w == 0) ? s0 : (w == 1) ? s1 : s2;
    unsigned short* dd = (w == 0) ? d0 : (w == 1) ? d1 : d2;
    dd[dj] = f2bf(s[j]);
  }
}

// ---------------------------------------------------------------- x prepass
// x[q][c][b][d] = bf16( tgt2[q,b,d] - mem[c,b,d] + rel[q,c,b,d] )
__global__ __launch_bounds__(256) void xprep_kernel(
    const float* __restrict__ rel, const float* __restrict__ memp,
    const float* __restrict__ tgt2, unsigned short* __restrict__ xg)
{
  const int total = Qn * Cn * Bn * Dm / 8;   // 4,194,304 groups of 8
  for (int i = blockIdx.x * 256 + threadIdx.x; i < total; i += gridDim.x * 256){
    int d8 = i & 31;
    int b  = (i >> 5) & 3;
    int c  = (i >> 7) & 511;
    int q  = i >> 16;
    const float4* rp = (const float4*)(rel + (size_t)i * 8);
    float4 r0 = rp[0], r1 = rp[1];
    const float4* mp = (const float4*)(memp + ((size_t)(c * 4 + b) * 256 + d8 * 8));
    float4 m0 = mp[0], m1 = mp[1];
    const float4* tp = (const float4*)(tgt2 + ((size_t)(q * 4 + b) * 256 + d8 * 8));
    float4 t0 = tp[0], t1 = tp[1];
    uint4 o;
    o.x = (unsigned int)f2bf(t0.x - m0.x + r0.x) | ((unsigned int)f2bf(t0.y - m0.y + r0.y) << 16);
    o.y = (unsigned int)f2bf(t0.z - m0.z + r0.z) | ((unsigned int)f2bf(t0.w - m0.w + r0.w) << 16);
    o.z = (unsigned int)f2bf(t1.x - m1.x + r1.x) | ((unsigned int)f2bf(t1.y - m1.y + r1.y) << 16);
    o.w = (unsigned int)f2bf(t1.z - m1.z + r1.z) | ((unsigned int)f2bf(t1.w - m1.w + r1.w) << 16);
    *(uint4*)(xg + (size_t)i * 8) = o;
  }
}

// ---------------------------------------------------------------- layernorm
__global__ __launch_bounds__(256) void ln_kernel(
    const float* __restrict__ in, const float* __restrict__ g, const float* __restrict__ bt,
    const float* __restrict__ addp,
    float* __restrict__ outF, unsigned short* __restrict__ outA, unsigned short* __restrict__ outB)
{
  const int r = blockIdx.x, t = threadIdx.x;
  float x = in[(size_t)r * 256 + t];
  float s = x, s2 = x * x;
  #pragma unroll
  for (int m = 1; m < 64; m <<= 1){ s += __shfl_xor(s, m, 64); s2 += __shfl_xor(s2, m, 64); }
  __shared__ float ls[8];
  int w = t >> 6, l = t & 63;
  if (l == 0){ ls[w] = s; ls[4 + w] = s2; }
  __syncthreads();
  s  = ls[0] + ls[1] + ls[2] + ls[3];
  s2 = ls[4] + ls[5] + ls[6] + ls[7];
  float mean = s * (1.f / 256.f);
  float var  = s2 * (1.f / 256.f) - mean * mean;
  float y = (x - mean) * rsqrtf(var + 1e-5f) * g[t] + bt[t];
  size_t o = (size_t)r * 256 + t;
  if (outF) outF[o] = y;
  if (outA) outA[o] = f2bf(y);
  if (outB) outB[o] = f2bf(y + addp[o]);
}

// ---------------------------------------------------------------- generic GEMM
// C[M,N] = act(alpha * A_bf16(M,K) @ W_bf16(N,K)^T + bias) (+resid)
// cmode==2: store Cf[(( (row&3)*512 + (row>>2) )*256 + col)]   ([b][c][f] for Mv0T)
__global__ __launch_bounds__(256, 4) void gemm_kernel(
    const unsigned short* __restrict__ A, const unsigned short* __restrict__ W,
    const float* __restrict__ bias, const float* __restrict__ resid,
    float* __restrict__ Cf, unsigned short* __restrict__ Cb,
    int M, int N, int K, float alpha, int relu, int cmode)
{
  __shared__ unsigned short As[64 * 64];
  __shared__ unsigned short Ws[64 * 64];
  const int tid = threadIdx.x;
  const int l = tid & 63;
  const int w = tid >> 6;
  const int wm = w >> 1, wn = w & 1;
  const int bm = blockIdx.x * 64, bn = blockIdx.y * 64;
  f32x4 acc[2][2] = {{{0,0,0,0},{0,0,0,0}},{{0,0,0,0},{0,0,0,0}}};

  for (int kc = 0; kc < K; kc += 64){
    __syncthreads();
    #pragma unroll
    for (int i = 0; i < 2; ++i){
      int idx = tid + i * 256;
      int r = idx >> 3, s = idx & 7;
      int byte = (s * 16) ^ ((r & 7) << 4);
      *(short8*)((char*)As + r * 128 + byte) = *(const short8*)(A + (size_t)(bm + r) * K + kc + s * 8);
      *(short8*)((char*)Ws + r * 128 + byte) = *(const short8*)(W + (size_t)(bn + r) * K + kc + s * 8);
    }
    __syncthreads();
    #pragma unroll
    for (int ks = 0; ks < 2; ++ks){
      short8 af[2], bf[2];
      af[0] = ldfrag(As, 128, wm * 32,      ks, l);
      af[1] = ldfrag(As, 128, wm * 32 + 16, ks, l);
      bf[0] = ldfrag(Ws, 128, wn * 32,      ks, l);
      bf[1] = ldfrag(Ws, 128, wn * 32 + 16, ks, l);
      #pragma unroll
      for (int i = 0; i < 2; ++i)
        #pragma unroll
        for (int j = 0; j < 2; ++j)
          acc[i][j] = mfma16(af[i], bf[j], acc[i][j]);
    }
  }
  #pragma unroll
  for (int i = 0; i < 2; ++i)
  #pragma unroll
  for (int j = 0; j < 2; ++j){
    int col = bn + wn * 32 + j * 16 + (l & 15);
    float bv = bias ? bias[col] : 0.f;
    #pragma unroll
    for (int u = 0; u < 4; ++u){
      int row = bm + wm * 32 + i * 16 + ((l >> 4) << 2) + u;
      float v = alpha * acc[i][j][u] + bv;
      if (relu) v = fmaxf(v, 0.f);
      if (resid) v += resid[(size_t)row * N + col];
      if (cmode == 2){
        Cf[(((size_t)(row & 3) * 512 + (row >> 2)) * 256) + col] = v;
      } else {
        if (Cf) Cf[(size_t)row * N + col] = v;
        if (Cb) Cb[(size_t)row * N + col] = f2bf(v);
      }
    }
  }
}

// ---------------------------------------------------------------- self-attention
__global__ __launch_bounds__(256) void attn_kernel(
    const float* __restrict__ qkp, const float* __restrict__ vp,
    unsigned short* __restrict__ attn_o)
{
  __shared__ float ks[128][33];
  __shared__ float vs[128][33];
  __shared__ float sc[128][129];
  const int bh = blockIdx.x;
  const int b = bh >> 3, h = bh & 7;
  const int tid = threadIdx.x;
  const int lrow = tid >> 1;
  const int half = tid & 1;
  {
    int s = tid >> 1;
    int d0 = half * 16;
    const float* kp = qkp + ((size_t)s * Bn + b) * 512 + 256 + h * 32 + d0;
    const float* vv = vp  + ((size_t)s * Bn + b) * 256 +       h * 32 + d0;
    #pragma unroll
    for (int d = 0; d < 16; d += 4){
      *(float4*)&ks[s][d0 + d] = *(const float4*)(kp + d);
      *(float4*)&vs[s][d0 + d] = *(const float4*)(vv + d);
    }
  }
  __syncthreads();
  float qv[32];
  const float* qp = qkp + ((size_t)lrow * Bn + b) * 512 + h * 32;
  #pragma unroll
  for (int d = 0; d < 32; ++d) qv[d] = qp[d];
  const float scale = 0.17677669529663687f;
  float mloc = -1e30f;
  for (int s2 = 0; s2 < 64; ++s2){
    int s = half * 64 + s2;
    float dot = 0.f;
    #pragma unroll
    for (int d = 0; d < 32; ++d) dot += qv[d] * ks[s][d];
    dot *= scale;
    sc[lrow][s] = dot;
    mloc = fmaxf(mloc, dot);
  }
  float m = fmaxf(mloc, __shfl_xor(mloc, 1, 64));
  float sum = 0.f;
  for (int s2 = 0; s2 < 64; ++s2){
    int s = half * 64 + s2;
    float e = __expf(sc[lrow][s] - m);
    sum += e;
    sc[lrow][s] = e;
  }
  sum += __shfl_xor(sum, 1, 64);
  float inv = 1.f / sum;
  float o[32];
  #pragma unroll
  for (int d = 0; d < 32; ++d) o[d] = 0.f;
  for (int s2 = 0; s2 < 64; ++s2){
    int s = half * 64 + s2;
    float e = sc[lrow][s];
    #pragma unroll
    for (int d = 0; d < 32; ++d) o[d] += e * vs[s][d];
  }
  #pragma unroll
  for (int d = 0; d < 32; ++d){
    o[d] += __shfl_xor(o[d], 1, 64);
    o[d] *= inv;
  }
  unsigned short* op = attn_o + ((size_t)lrow * Bn + b) * 256 + h * 32 + half * 16;
  #pragma unroll
  for (int d = 0; d < 16; ++d) op[d] = f2bf(o[half * 16 + d]);
}

// ---------------------------------------------------------------- relation branch (fused)
// block = (q,b) via bijective XCD swizzle, 1024 threads = 16 waves (wr 2 x wc 8)
// x (bf16, precomputed) staged async via global_load_lds with pre-swizzled source.
// h = relu(x@W1 + b1) -> hT ; v2 = x@Wv + Mv0T[b,c,f] + T2c[qb,f] (regs)
// sim = (h@W2 + b2)/16 ; online softmax over c per channel f
__global__ __launch_bounds__(1024, 4) void relation_kernel(
    const unsigned short* __restrict__ xg,
    const unsigned short* __restrict__ W1p,
    const unsigned short* __restrict__ Wvp,
    const unsigned short* __restrict__ W2p,
    const float* __restrict__ b1,
    const float* __restrict__ T2c,
    const float* __restrict__ Mv0T,
    const float* __restrict__ b2,
    unsigned short* __restrict__ outT)
{
  __shared__ unsigned short xT[128 * 256];   // 64KB
  __shared__ unsigned short hT[128 * 256];   // 64KB

  // XCD-aware swizzle: 512 blocks = 8 XCDs x 64; each XCD gets one b, 64 q's
  const int sw = (blockIdx.x & 7) * 64 + (blockIdx.x >> 3);
  const int q = sw & 127, b = sw >> 7;
  const int bid = q * 4 + b;
  const int tid = threadIdx.x;
  const int w = tid >> 6;
  const int l = tid & 63;
  const int wr = w >> 3;                      // 0..1 row half (64 rows)
  const int wc = w & 7;                       // 0..7 f col (32 f)
  const int l31 = l & 31;
  const int kh = l >> 5;
  const int f = wc * 32 + l31;

  const float b1v = b1[f];
  const float b2v = b2[f];
  const float tcv = T2c[(size_t)bid * 256 + f];

  const unsigned short* w1base = W1p + ((size_t)kh * 256 + f) * 8;
  const unsigned short* wvbase = Wvp + ((size_t)kh * 256 + f) * 8;
  const unsigned short* w2base = W2p + ((size_t)kh * 256 + f) * 8;

  // stage tile ct: wave w stages rows [w*8, w*8+8), 4 issues of 2 rows each
  auto stage = [&](int ct){
    const int c0 = ct * 128;
    #pragma unroll
    for (int i = 0; i < 4; ++i){
      int rowp = w * 8 + i * 2;
      int row = rowp + (l >> 5);
      int c = c0 + row;
      const char* src = (const char*)(xg + (((size_t)q * Cn + c) * Bn + b) * Dm)
                      + (((l & 31) * 16) ^ ((row & 7) << 4));
      gload_lds16(src, (char*)xT + rowp * 512);
    }
  };

  float sm = -1e30f, sl = 0.f, sa = 0.f;

  stage(0);
  asm volatile("s_waitcnt vmcnt(0)" ::: "memory");
  __syncthreads();

  for (int ct = 0; ct < 4; ++ct){
    const int c0 = ct * 128;

    // ---- fused GEMM1a (h = x@W1) + GEMM1b (v2 = x@Wv)
    f32x16 acc1[2], accv[2];
    #pragma unroll
    for (int m = 0; m < 2; ++m){
      #pragma unroll
      for (int r = 0; r < 16; ++r){ acc1[m][r] = 0.f; accv[m][r] = 0.f; }
    }
    #pragma unroll
    for (int kc = 0; kc < 16; ++kc){
      short8 a0 = ldfrag32(xT, wr * 64,      kc, l);
      short8 a1 = ldfrag32(xT, wr * 64 + 32, kc, l);
      short8 bw1 = *(const short8*)(w1base + kc * 4096);
      short8 bwv = *(const short8*)(wvbase + kc * 4096);
      acc1[0] = mfma32(a0, bw1, acc1[0]);
      acc1[1] = mfma32(a1, bw1, acc1[1]);
      accv[0] = mfma32(a0, bwv, accv[0]);
      accv[1] = mfma32(a1, bwv, accv[1]);
    }
    // h epilogue -> hT (bf16, swizzled)
    #pragma unroll
    for (int m = 0; m < 2; ++m){
      #pragma unroll
      for (int reg = 0; reg < 16; ++reg){
        int rr = (reg & 3) + 8 * (reg >> 2) + 4 * kh;
        int row = wr * 64 + m * 32 + rr;
        float hv = fmaxf(acc1[m][reg] + b1v, 0.f);
        int byte = (f * 2) ^ ((row & 7) << 4);
        *(unsigned short*)((char*)hT + row * 512 + byte) = f2bf(hv);
      }
    }
    // v2 epilogue -> packed bf16 registers (Mv0T now [b][c][f]: lane-coalesced)
    unsigned int vreg[2][8];
    #pragma unroll
    for (int m = 0; m < 2; ++m){
      #pragma unroll
      for (int rg = 0; rg < 8; ++rg){
        int rr0 = ((rg * 2) & 3) + 8 * ((rg * 2) >> 2) + 4 * kh;
        int c0r = c0 + wr * 64 + m * 32 + rr0;
        float mva = Mv0T[((size_t)b * 512 + c0r) * 256 + f];
        float mvb = Mv0T[((size_t)b * 512 + c0r + 1) * 256 + f];
        float v0 = accv[m][rg * 2 + 0] + mva + tcv;
        float v1 = accv[m][rg * 2 + 1] + mvb + tcv;
        vreg[m][rg] = (unsigned int)f2bf(v0) | ((unsigned int)f2bf(v1) << 16);
      }
    }
    __syncthreads();   // S1: xT fully consumed, hT complete

    // ---- issue async stage of next x tile (overlaps GEMM2 + softmax)
    if (ct < 3) stage(ct + 1);

    // ---- GEMM2: sim = (h@W2 + b2)/16
    f32x16 acc2[2];
    #pragma unroll
    for (int m = 0; m < 2; ++m){
      #pragma unroll
      for (int r = 0; r < 16; ++r) acc2[m][r] = 0.f;
    }
    #pragma unroll
    for (int kc = 0; kc < 16; ++kc){
      short8 h0 = ldfrag32(hT, wr * 64,      kc, l);
      short8 h1 = ldfrag32(hT, wr * 64 + 32, kc, l);
      short8 bw2 = *(const short8*)(w2base + kc * 4096);
      acc2[0] = mfma32(h0, bw2, acc2[0]);
      acc2[1] = mfma32(h1, bw2, acc2[1]);
    }
    // online softmax update over this 128-row c-tile
    float tmax = -1e30f;
    #pragma unroll
    for (int m = 0; m < 2; ++m){
      #pragma unroll
      for (int reg = 0; reg < 16; ++reg){
        float sv = (acc2[m][reg] + b2v) * 0.0625f;
        acc2[m][reg] = sv;
        tmax = fmaxf(tmax, sv);
      }
    }
    tmax = fmaxf(tmax, __shfl_xor(tmax, 32, 64));
    float mnew = fmaxf(sm, tmax);
    float corr = __expf(sm - mnew);
    float ps = 0.f, pa = 0.f;
    #pragma unroll
    for (int m = 0; m < 2; ++m){
      #pragma unroll
      for (int rg = 0; rg < 8; ++rg){
        float e0 = __expf(acc2[m][rg * 2 + 0] - mnew);
        float e1 = __expf(acc2[m][rg * 2 + 1] - mnew);
        unsigned int vp2 = vreg[m][rg];
        ps += e0 + e1;
        pa += e0 * bflo2f(vp2) + e1 * bfhi2f(vp2);
      }
    }
    ps += __shfl_xor(ps, 32, 64);
    pa += __shfl_xor(pa, 32, 64);
    sl = sl * corr + ps;
    sa = sa * corr + pa;
    sm = mnew;

    // stage loads must land before next GEMM1 reads xT
    asm volatile("s_waitcnt vmcnt(0)" ::: "memory");
    __syncthreads();   // S2
  }

  // ---- merge the two wr halves per f
  float* mb = (float*)xT;
  if (l < 32){
    int idx = ((wr * 8 + wc) * 32 + l31) * 3;
    mb[idx] = sm; mb[idx + 1] = sl; mb[idx + 2] = sa;
  }
  __syncthreads();
  if (tid < 256){
    int ff = tid;
    int i0 = ((ff >> 5) * 32 + (ff & 31)) * 3;
    int i1 = ((8 + (ff >> 5)) * 32 + (ff & 31)) * 3;
    float m0 = mb[i0], l0 = mb[i0 + 1], a0 = mb[i0 + 2];
    float m1 = mb[i1], l1 = mb[i1 + 1], a1 = mb[i1 + 2];
    float M = fmaxf(m0, m1);
    float e0 = __expf(m0 - M), e1 = __expf(m1 - M);
    float L = l0 * e0 + l1 * e1;
    float A = a0 * e0 + a1 * e1;
    outT[(size_t)bid * 256 + ff] = f2bf(A / L);
  }
}

// ---------------------------------------------------------------- launch
extern "C" void kernel_launch(void* const* d_in, const int* in_sizes, int n_in,
                              void* d_out, int out_size, void* d_ws, size_t ws_size,
                              hipStream_t stream)
{
  const float* tgt  = (const float*)d_in[0];
  const float* mem  = (const float*)d_in[1];
  const float* qpos = (const float*)d_in[2];
  const float* rel  = (const float*)d_in[3];
  const float* ln1g = (const float*)d_in[4];
  const float* ln1b = (const float*)d_in[5];
  const float* ln2g = (const float*)d_in[6];
  const float* ln2b = (const float*)d_in[7];
  const float* ln3g = (const float*)d_in[8];
  const float* ln3b = (const float*)d_in[9];
  const float* inw  = (const float*)d_in[10];
  const float* inb  = (const float*)d_in[11];
  const float* aow  = (const float*)d_in[12];
  const float* aob  = (const float*)d_in[13];
  const float* m1w  = (const float*)d_in[14];
  const float* m1b  = (const float*)d_in[15];
  const float* m2w  = (const float*)d_in[16];
  const float* m2b  = (const float*)d_in[17];
  const float* vw   = (const float*)d_in[18];
  const float* vb   = (const float*)d_in[19];
  const float* ow   = (const float*)d_in[20];
  const float* ob   = (const float*)d_in[21];
  const float* f1w  = (const float*)d_in[22];
  const float* f1b  = (const float*)d_in[23];
  const float* f2w  = (const float*)d_in[24];
  const float* f2b  = (const float*)d_in[25];

  char* ws = (char*)d_ws;
  size_t off = 0;
  auto alloc = [&](size_t bytes) -> char* {
    char* p = ws + off; off += (bytes + 255) & ~size_t(255); return p;
  };
  unsigned short* xg      = (unsigned short*)alloc((size_t)Qn * Cn * Bn * Dm * 2);  // 67MB
  unsigned short* inw_bf  = (unsigned short*)alloc(768 * 256 * 2);
  unsigned short* aow_bf  = (unsigned short*)alloc(256 * 256 * 2);
  unsigned short* ow_bf   = (unsigned short*)alloc(256 * 256 * 2);
  unsigned short* f1w_bf  = (unsigned short*)alloc(1024 * 256 * 2);
  unsigned short* f2w_bf  = (unsigned short*)alloc(256 * 1024 * 2);
  unsigned short* mem_bf  = (unsigned short*)alloc(2048 * 256 * 2);
  unsigned short* vw_bf   = (unsigned short*)alloc(256 * 256 * 2);
  unsigned short* m1w_pk  = (unsigned short*)alloc(256 * 256 * 2);
  unsigned short* vw_pk   = (unsigned short*)alloc(256 * 256 * 2);
  unsigned short* m2w_pk  = (unsigned short*)alloc(256 * 256 * 2);
  unsigned short* t21_bf  = (unsigned short*)alloc(512 * 256 * 2);
  unsigned short* qk_bf   = (unsigned short*)alloc(512 * 256 * 2);
  float*          qkp     = (float*)alloc(512 * 512 * 4);
  float*          vp      = (float*)alloc(512 * 256 * 4);
  unsigned short* ao_bf   = (unsigned short*)alloc(512 * 256 * 2);
  float*          tgta    = (float*)alloc(512 * 256 * 4);
  float*          t22_f   = (float*)alloc(512 * 256 * 4);
  unsigned short* t22_bf  = (unsigned short*)alloc(512 * 256 * 2);
  float*          T2c     = (float*)alloc(512 * 256 * 4);
  float*          Mv0T    = (float*)alloc(4 * 512 * 256 * 4);
  unsigned short* trel_bf = (unsigned short*)alloc(512 * 256 * 2);
  float*          tgtr    = (float*)alloc(512 * 256 * 4);
  unsigned short* t23_bf  = (unsigned short*)alloc(512 * 256 * 2);
  unsigned short* ffh_bf  = (unsigned short*)alloc(512 * 1024 * 2);

  conv_lin_kernel<<<2048, 256, 0, stream>>>(inw, inw_bf, aow, aow_bf, ow, ow_bf,
      f1w, f1w_bf, f2w, f2w_bf, mem, mem_bf, vw, vw_bf);
  conv_pk_kernel<<<768, 256, 0, stream>>>(m1w, m1w_pk, vw, vw_pk, m2w, m2w_pk);

  // ln1 -> tgt2_1 (bf16), qk = tgt2_1 + query_pos (bf16)
  ln_kernel<<<512, 256, 0, stream>>>(tgt, ln1g, ln1b, qpos, nullptr, t21_bf, qk_bf);

  // q|k projection (N=512) and v projection (N=256)
  gemm_kernel<<<dim3(8, 8), 256, 0, stream>>>(qk_bf, inw_bf, inb, nullptr,
      qkp, nullptr, 512, 512, 256, 1.f, 0, 0);
  gemm_kernel<<<dim3(8, 4), 256, 0, stream>>>(t21_bf, inw_bf + 512 * 256, inb + 512, nullptr,
      vp, nullptr, 512, 256, 256, 1.f, 0, 0);

  attn_kernel<<<32, 256, 0, stream>>>(qkp, vp, ao_bf);

  // out-proj + residual tgt -> tgta
  gemm_kernel<<<dim3(8, 4), 256, 0, stream>>>(ao_bf, aow_bf, aob, tgt,
      tgta, nullptr, 512, 256, 256, 1.f, 0, 0);

  // ln2 -> t22 (f32 + bf16)
  ln_kernel<<<512, 256, 0, stream>>>(tgta, ln2g, ln2b, nullptr, t22_f, t22_bf, nullptr);

  // T2c = vb - tgt2@Wv ; Mv0T[b][c][f] = 2*mem@Wv
  gemm_kernel<<<dim3(8, 4), 256, 0, stream>>>(t22_bf, vw_bf, vb, nullptr,
      T2c, nullptr, 512, 256, 256, -1.f, 0, 0);
  gemm_kernel<<<dim3(32, 4), 256, 0, stream>>>(mem_bf, vw_bf, nullptr, nullptr,
      Mv0T, nullptr, 2048, 256, 256, 2.f, 0, 2);

  // x = bf16(tgt2 - mem + rel)
  xprep_kernel<<<2048, 256, 0, stream>>>(rel, mem, t22_f, xg);

  relation_kernel<<<512, 1024, 0, stream>>>(xg, m1w_pk, vw_pk, m2w_pk,
      m1b, T2c, Mv0T, m2b, trel_bf);

  // t = relu(t@o_w + o_b) + t22
  gemm_kernel<<<dim3(8, 4), 256, 0, stream>>>(trel_bf, ow_bf, ob, t22_f,
      tgtr, nullptr, 512, 256, 256, 1.f, 1, 0);

  // ln3 -> bf16
  ln_kernel<<<512, 256, 0, stream>>>(tgtr, ln3g, ln3b, nullptr, nullptr, t23_bf, nullptr);

  // ffn
  gemm_kernel<<<dim3(8, 16), 256, 0, stream>>>(t23_bf, f1w_bf, f1b, nullptr,
      nullptr, ffh_bf, 512, 1024, 256, 1.f, 1, 0);
  gemm_kernel<<<dim3(8, 4), 256, 0, stream>>>(ffh_bf, f2w_bf, f2b, tgtr,
      (float*)d_out, nullptr, 512, 256, 1024, 1.f, 0, 0);
}

// Round 4
// 659.570 us; speedup vs baseline: 1.3872x; 1.3872x over previous
//
#include <hip/hip_runtime.h>
#include <hip/hip_bf16.h>
#include <cstdint>
#include <cstddef>

#define DEV __device__ __forceinline__

typedef __attribute__((ext_vector_type(8))) short short8;
typedef __attribute__((ext_vector_type(4))) float f32x4;
typedef __attribute__((ext_vector_type(16))) float f32x16;

constexpr int Dm  = 256;
constexpr int Qn  = 128;
constexpr int Cn  = 512;
constexpr int Bn  = 4;

DEV unsigned short f2bf(float f){
  unsigned int u = __builtin_bit_cast(unsigned int, f);
  u += 0x7fffu + ((u >> 16) & 1u);
  return (unsigned short)(u >> 16);
}

DEV float bflo2f(unsigned int lo){ return __builtin_bit_cast(float, lo << 16); }

DEV f32x4 mfma16(short8 a, short8 b, f32x4 c){
  return __builtin_amdgcn_mfma_f32_16x16x32_bf16(a, b, c, 0, 0, 0);
}
DEV f32x16 mfma32(short8 a, short8 b, f32x16 c){
  return __builtin_amdgcn_mfma_f32_32x32x16_bf16(a, b, c, 0, 0, 0);
}

// 16x16x32 fragment load from XOR-swizzled LDS tile (rowbytes bytes/row)
DEV short8 ldfrag(const unsigned short* buf, int rowbytes, int row0, int ks, int l){
  int r = row0 + (l & 15);
  int byte = (ks * 64 + ((l >> 4) * 16)) ^ ((r & 7) << 4);
  return *(const short8*)((const char*)buf + r * rowbytes + byte);
}

// async global->LDS, 16 bytes per lane; LDS dest = wave-uniform base + lane*16
DEV void gload_lds16(const void* g, void* lds){
  __builtin_amdgcn_global_load_lds(
      (const __attribute__((address_space(1))) unsigned int*)g,
      (__attribute__((address_space(3))) unsigned int*)lds, 16, 0, 0);
}

// B-fragment read from LDS-resident weight [256 f][512B row], 16-slot XOR swizzle
DEV short8 wfrag(const unsigned short* Wt, int f, int kc, int kh){
  int byte = f * 512 + ((kc * 32 + kh * 16) ^ ((f & 15) << 4));
  return *(const short8*)((const char*)Wt + byte);
}

// build bf16 x-fragment on the fly: x = tgt2 - mem + rel (8 consecutive d)
DEV short8 xfrag(const float* r, const float* m, const float* t){
  float4 r0 = *(const float4*)r, r1 = *(const float4*)(r + 4);
  float4 m0 = *(const float4*)m, m1 = *(const float4*)(m + 4);
  float4 t0 = *(const float4*)t, t1 = *(const float4*)(t + 4);
  union { unsigned int u[4]; short8 s; } cv;
  cv.u[0] = (unsigned int)f2bf(t0.x - m0.x + r0.x) | ((unsigned int)f2bf(t0.y - m0.y + r0.y) << 16);
  cv.u[1] = (unsigned int)f2bf(t0.z - m0.z + r0.z) | ((unsigned int)f2bf(t0.w - m0.w + r0.w) << 16);
  cv.u[2] = (unsigned int)f2bf(t1.x - m1.x + r1.x) | ((unsigned int)f2bf(t1.y - m1.y + r1.y) << 16);
  cv.u[3] = (unsigned int)f2bf(t1.z - m1.z + r1.z) | ((unsigned int)f2bf(t1.w - m1.w + r1.w) << 16);
  return cv.s;
}

// ---------------------------------------------------------------- converts
__global__ __launch_bounds__(256) void conv_lin_kernel(
    const float* s0, unsigned short* d0,   // in_proj 196608
    const float* s1, unsigned short* d1,   // attn_out 65536
    const float* s2, unsigned short* d2,   // o_w 65536
    const float* s3, unsigned short* d3,   // ff1 262144
    const float* s4, unsigned short* d4,   // ff2 262144
    const float* s5, unsigned short* d5,   // memory 524288
    const float* s6, unsigned short* d6,   // v_w 65536
    const float* s7, unsigned short* d7,   // mlp1 65536
    const float* s8, unsigned short* d8)   // mlp2 65536
{
  const int total = 196608 + 65536 + 65536 + 262144 + 262144 + 524288 + 65536 + 65536 + 65536;
  for (int i = blockIdx.x * 256 + threadIdx.x; i < total; i += gridDim.x * 256){
    int j = i;
    if (j < 196608){ d0[j] = f2bf(s0[j]); continue; } j -= 196608;
    if (j < 65536) { d1[j] = f2bf(s1[j]); continue; } j -= 65536;
    if (j < 65536) { d2[j] = f2bf(s2[j]); continue; } j -= 65536;
    if (j < 262144){ d3[j] = f2bf(s3[j]); continue; } j -= 262144;
    if (j < 262144){ d4[j] = f2bf(s4[j]); continue; } j -= 262144;
    if (j < 524288){ d5[j] = f2bf(s5[j]); continue; } j -= 524288;
    if (j < 65536) { d6[j] = f2bf(s6[j]); continue; } j -= 65536;
    if (j < 65536) { d7[j] = f2bf(s7[j]); continue; } j -= 65536;
    d8[j] = f2bf(s8[j]);
  }
}

// ---------------------------------------------------------------- layernorm
__global__ __launch_bounds__(256) void ln_kernel(
    const float* __restrict__ in, const float* __restrict__ g, const float* __restrict__ bt,
    const float* __restrict__ addp,
    float* __restrict__ outF, unsigned short* __restrict__ outA, unsigned short* __restrict__ outB)
{
  const int r = blockIdx.x, t = threadIdx.x;
  float x = in[(size_t)r * 256 + t];
  float s = x, s2 = x * x;
  #pragma unroll
  for (int m = 1; m < 64; m <<= 1){ s += __shfl_xor(s, m, 64); s2 += __shfl_xor(s2, m, 64); }
  __shared__ float ls[8];
  int w = t >> 6, l = t & 63;
  if (l == 0){ ls[w] = s; ls[4 + w] = s2; }
  __syncthreads();
  s  = ls[0] + ls[1] + ls[2] + ls[3];
  s2 = ls[4] + ls[5] + ls[6] + ls[7];
  float mean = s * (1.f / 256.f);
  float var  = s2 * (1.f / 256.f) - mean * mean;
  float y = (x - mean) * rsqrtf(var + 1e-5f) * g[t] + bt[t];
  size_t o = (size_t)r * 256 + t;
  if (outF) outF[o] = y;
  if (outA) outA[o] = f2bf(y);
  if (outB) outB[o] = f2bf(y + addp[o]);
}

// ---------------------------------------------------------------- generic GEMM
// C[M,N] = act(alpha * A_bf16(M,K) @ W_bf16(N,K)^T + bias) (+resid)
// cmode==2: store Cf[(( (row&3)*512 + (row>>2) )*256 + col)]   ([b][c][f] for Mv0T)
__global__ __launch_bounds__(256, 4) void gemm_kernel(
    const unsigned short* __restrict__ A, const unsigned short* __restrict__ W,
    const float* __restrict__ bias, const float* __restrict__ resid,
    float* __restrict__ Cf, unsigned short* __restrict__ Cb,
    int M, int N, int K, float alpha, int relu, int cmode)
{
  __shared__ unsigned short As[64 * 64];
  __shared__ unsigned short Ws[64 * 64];
  const int tid = threadIdx.x;
  const int l = tid & 63;
  const int w = tid >> 6;
  const int wm = w >> 1, wn = w & 1;
  const int bm = blockIdx.x * 64, bn = blockIdx.y * 64;
  f32x4 acc[2][2] = {{{0,0,0,0},{0,0,0,0}},{{0,0,0,0},{0,0,0,0}}};

  for (int kc = 0; kc < K; kc += 64){
    __syncthreads();
    #pragma unroll
    for (int i = 0; i < 2; ++i){
      int idx = tid + i * 256;
      int r = idx >> 3, s = idx & 7;
      int byte = (s * 16) ^ ((r & 7) << 4);
      *(short8*)((char*)As + r * 128 + byte) = *(const short8*)(A + (size_t)(bm + r) * K + kc + s * 8);
      *(short8*)((char*)Ws + r * 128 + byte) = *(const short8*)(W + (size_t)(bn + r) * K + kc + s * 8);
    }
    __syncthreads();
    #pragma unroll
    for (int ks = 0; ks < 2; ++ks){
      short8 af[2], bf[2];
      af[0] = ldfrag(As, 128, wm * 32,      ks, l);
      af[1] = ldfrag(As, 128, wm * 32 + 16, ks, l);
      bf[0] = ldfrag(Ws, 128, wn * 32,      ks, l);
      bf[1] = ldfrag(Ws, 128, wn * 32 + 16, ks, l);
      #pragma unroll
      for (int i = 0; i < 2; ++i)
        #pragma unroll
        for (int j = 0; j < 2; ++j)
          acc[i][j] = mfma16(af[i], bf[j], acc[i][j]);
    }
  }
  #pragma unroll
  for (int i = 0; i < 2; ++i)
  #pragma unroll
  for (int j = 0; j < 2; ++j){
    int col = bn + wn * 32 + j * 16 + (l & 15);
    float bv = bias ? bias[col] : 0.f;
    #pragma unroll
    for (int u = 0; u < 4; ++u){
      int row = bm + wm * 32 + i * 16 + ((l >> 4) << 2) + u;
      float v = alpha * acc[i][j][u] + bv;
      if (relu) v = fmaxf(v, 0.f);
      if (resid) v += resid[(size_t)row * N + col];
      if (cmode == 2){
        Cf[(((size_t)(row & 3) * 512 + (row >> 2)) * 256) + col] = v;
      } else {
        if (Cf) Cf[(size_t)row * N + col] = v;
        if (Cb) Cb[(size_t)row * N + col] = f2bf(v);
      }
    }
  }
}

// ---------------------------------------------------------------- self-attention
__global__ __launch_bounds__(256) void attn_kernel(
    const float* __restrict__ qkp, const float* __restrict__ vp,
    unsigned short* __restrict__ attn_o)
{
  __shared__ float ks[128][33];
  __shared__ float vs[128][33];
  __shared__ float sc[128][129];
  const int bh = blockIdx.x;
  const int b = bh >> 3, h = bh & 7;
  const int tid = threadIdx.x;
  const int lrow = tid >> 1;
  const int half = tid & 1;
  {
    int s = tid >> 1;
    int d0 = half * 16;
    const float* kp = qkp + ((size_t)s * Bn + b) * 512 + 256 + h * 32 + d0;
    const float* vv = vp  + ((size_t)s * Bn + b) * 256 +       h * 32 + d0;
    #pragma unroll
    for (int d = 0; d < 16; d += 4){
      *(float4*)&ks[s][d0 + d] = *(const float4*)(kp + d);
      *(float4*)&vs[s][d0 + d] = *(const float4*)(vv + d);
    }
  }
  __syncthreads();
  float qv[32];
  const float* qp = qkp + ((size_t)lrow * Bn + b) * 512 + h * 32;
  #pragma unroll
  for (int d = 0; d < 32; ++d) qv[d] = qp[d];
  const float scale = 0.17677669529663687f;
  float mloc = -1e30f;
  for (int s2 = 0; s2 < 64; ++s2){
    int s = half * 64 + s2;
    float dot = 0.f;
    #pragma unroll
    for (int d = 0; d < 32; ++d) dot += qv[d] * ks[s][d];
    dot *= scale;
    sc[lrow][s] = dot;
    mloc = fmaxf(mloc, dot);
  }
  float m = fmaxf(mloc, __shfl_xor(mloc, 1, 64));
  float sum = 0.f;
  for (int s2 = 0; s2 < 64; ++s2){
    int s = half * 64 + s2;
    float e = __expf(sc[lrow][s] - m);
    sum += e;
    sc[lrow][s] = e;
  }
  sum += __shfl_xor(sum, 1, 64);
  float inv = 1.f / sum;
  float o[32];
  #pragma unroll
  for (int d = 0; d < 32; ++d) o[d] = 0.f;
  for (int s2 = 0; s2 < 64; ++s2){
    int s = half * 64 + s2;
    float e = sc[lrow][s];
    #pragma unroll
    for (int d = 0; d < 32; ++d) o[d] += e * vs[s][d];
  }
  #pragma unroll
  for (int d = 0; d < 32; ++d){
    o[d] += __shfl_xor(o[d], 1, 64);
    o[d] *= inv;
  }
  unsigned short* op = attn_o + ((size_t)lrow * Bn + b) * 256 + h * 32 + half * 16;
  #pragma unroll
  for (int d = 0; d < 16; ++d) op[d] = f2bf(o[half * 16 + d]);
}

// ---------------------------------------------------------------- relation pass 1: h
// block = (qb, chalf). W1 in LDS. wave owns 32 c-rows x 128 f (4 fblocks).
// h[qb][c][f] = relu(x @ W1 + b1), x built on the fly.
__global__ __launch_bounds__(1024) void hpass_kernel(
    const float* __restrict__ rel, const float* __restrict__ memp,
    const float* __restrict__ t22,
    const unsigned short* __restrict__ W1g, const float* __restrict__ b1,
    unsigned short* __restrict__ hsim)
{
  __shared__ unsigned short Wt[65536];
  const int bid = blockIdx.x;
  const int qb = bid >> 1, ch = bid & 1;
  const int q = qb >> 2, b = qb & 3;
  const int tid = threadIdx.x;
  const int w = tid >> 6, l = tid & 63;
  const int rb = w >> 1, fg = w & 1;
  const int l31 = l & 31, kh = l >> 5;
  #pragma unroll
  for (int i = 0; i < 8; ++i){
    int s = (tid + i * 1024) * 16;
    int row = s >> 9, inr = s & 511;
    gload_lds16((const char*)W1g + row * 512 + (inr ^ ((row & 15) << 4)),
                (char*)Wt + (w * 64 + i * 1024) * 16);
  }
  asm volatile("s_waitcnt vmcnt(0)" ::: "memory");
  __syncthreads();

  const int c0 = ch * 256 + rb * 32;
  const float* relr = rel + (((size_t)q * 512 + c0 + l31) * 4 + b) * 256 + kh * 8;
  const float* memr = memp + ((size_t)(c0 + l31) * 4 + b) * 256 + kh * 8;
  const float* t2r  = t22 + (size_t)qb * 256 + kh * 8;

  f32x16 acc[4];
  #pragma unroll
  for (int fb = 0; fb < 4; ++fb)
    #pragma unroll
    for (int r = 0; r < 16; ++r) acc[fb][r] = 0.f;

  #pragma unroll
  for (int kc = 0; kc < 16; ++kc){
    short8 a = xfrag(relr + kc * 16, memr + kc * 16, t2r + kc * 16);
    #pragma unroll
    for (int fb = 0; fb < 4; ++fb){
      short8 bw = wfrag(Wt, fg * 128 + fb * 32 + l31, kc, kh);
      acc[fb] = mfma32(a, bw, acc[fb]);
    }
  }
  #pragma unroll
  for (int fb = 0; fb < 4; ++fb){
    int f = fg * 128 + fb * 32 + l31;
    float bv = b1[f];
    #pragma unroll
    for (int reg = 0; reg < 16; ++reg){
      int c = c0 + (reg & 3) + 8 * (reg >> 2) + 4 * kh;
      hsim[(size_t)qb * 131072 + (size_t)c * 256 + f] = f2bf(fmaxf(acc[fb][reg] + bv, 0.f));
    }
  }
}

// ---------------------------------------------------------------- relation pass 2: sim (in-place over h)
// sim = (h @ W2 + b2)/16, bf16, overwrites hsim. Row-exclusive waves; one barrier
// between all reads (MFMA loop) and all writes.
__global__ __launch_bounds__(1024) void simpass_kernel(
    const unsigned short* __restrict__ W2g, const float* __restrict__ b2,
    unsigned short* __restrict__ hsim)
{
  __shared__ unsigned short Wt[65536];
  const int bid = blockIdx.x;
  const int qb = bid >> 1, ch = bid & 1;
  const int tid = threadIdx.x;
  const int w = tid >> 6, l = tid & 63;
  const int rb = w >> 1, fg = w & 1;
  const int l31 = l & 31, kh = l >> 5;
  #pragma unroll
  for (int i = 0; i < 8; ++i){
    int s = (tid + i * 1024) * 16;
    int row = s >> 9, inr = s & 511;
    gload_lds16((const char*)W2g + row * 512 + (inr ^ ((row & 15) << 4)),
                (char*)Wt + (w * 64 + i * 1024) * 16);
  }
  asm volatile("s_waitcnt vmcnt(0)" ::: "memory");
  __syncthreads();

  const int c0 = ch * 256 + rb * 32;
  const unsigned short* hr = hsim + (size_t)qb * 131072 + (size_t)(c0 + l31) * 256 + kh * 8;

  f32x16 acc[4];
  #pragma unroll
  for (int fb = 0; fb < 4; ++fb)
    #pragma unroll
    for (int r = 0; r < 16; ++r) acc[fb][r] = 0.f;

  #pragma unroll
  for (int kc = 0; kc < 16; ++kc){
    short8 a = *(const short8*)(hr + kc * 16);
    #pragma unroll
    for (int fb = 0; fb < 4; ++fb){
      short8 bw = wfrag(Wt, fg * 128 + fb * 32 + l31, kc, kh);
      acc[fb] = mfma32(a, bw, acc[fb]);
    }
  }
  // stash sim bf16 in regs, barrier (all h reads done), then overwrite
  unsigned int st[4][8];
  #pragma unroll
  for (int fb = 0; fb < 4; ++fb){
    float bv = b2[fg * 128 + fb * 32 + l31];
    #pragma unroll
    for (int rp = 0; rp < 8; ++rp){
      float s0 = (acc[fb][rp * 2 + 0] + bv) * 0.0625f;
      float s1 = (acc[fb][rp * 2 + 1] + bv) * 0.0625f;
      st[fb][rp] = (unsigned int)f2bf(s0) | ((unsigned int)f2bf(s1) << 16);
    }
  }
  __syncthreads();
  #pragma unroll
  for (int fb = 0; fb < 4; ++fb){
    int f = fg * 128 + fb * 32 + l31;
    #pragma unroll
    for (int rp = 0; rp < 8; ++rp){
      int reg0 = rp * 2;
      int ca = c0 + (reg0 & 3) + 8 * (reg0 >> 2) + 4 * kh;
      hsim[(size_t)qb * 131072 + (size_t)ca * 256 + f] = (unsigned short)(st[fb][rp] & 0xffff);
      hsim[(size_t)qb * 131072 + (size_t)(ca + 1) * 256 + f] = (unsigned short)(st[fb][rp] >> 16);
    }
  }
}

// ---------------------------------------------------------------- relation pass 3: output partials
// v2 = x@Wv + Mv0T[b,c,f] + T2c[qb,f]; e = exp(sim); partT += e*v2, partL += e.
__global__ __launch_bounds__(1024) void outpass_kernel(
    const float* __restrict__ rel, const float* __restrict__ memp,
    const float* __restrict__ t22,
    const unsigned short* __restrict__ Wvg,
    const unsigned short* __restrict__ hsim,
    const float* __restrict__ Mv0T, const float* __restrict__ T2c,
    float* __restrict__ partT, float* __restrict__ partL)
{
  __shared__ unsigned short Wt[65536];
  const int bid = blockIdx.x;
  const int qb = bid >> 1, ch = bid & 1;
  const int q = qb >> 2, b = qb & 3;
  const int tid = threadIdx.x;
  const int w = tid >> 6, l = tid & 63;
  const int rb = w >> 1, fg = w & 1;
  const int l31 = l & 31, kh = l >> 5;
  #pragma unroll
  for (int i = 0; i < 8; ++i){
    int s = (tid + i * 1024) * 16;
    int row = s >> 9, inr = s & 511;
    gload_lds16((const char*)Wvg + row * 512 + (inr ^ ((row & 15) << 4)),
                (char*)Wt + (w * 64 + i * 1024) * 16);
  }
  asm volatile("s_waitcnt vmcnt(0)" ::: "memory");
  __syncthreads();

  const int c0 = ch * 256 + rb * 32;
  const float* relr = rel + (((size_t)q * 512 + c0 + l31) * 4 + b) * 256 + kh * 8;
  const float* memr = memp + ((size_t)(c0 + l31) * 4 + b) * 256 + kh * 8;
  const float* t2r  = t22 + (size_t)qb * 256 + kh * 8;

  f32x16 acc[4];
  #pragma unroll
  for (int fb = 0; fb < 4; ++fb)
    #pragma unroll
    for (int r = 0; r < 16; ++r) acc[fb][r] = 0.f;

  #pragma unroll
  for (int kc = 0; kc < 16; ++kc){
    short8 a = xfrag(relr + kc * 16, memr + kc * 16, t2r + kc * 16);
    #pragma unroll
    for (int fb = 0; fb < 4; ++fb){
      short8 bw = wfrag(Wt, fg * 128 + fb * 32 + l31, kc, kh);
      acc[fb] = mfma32(a, bw, acc[fb]);
    }
  }

  float tacc[4], lacc[4];
  #pragma unroll
  for (int fb = 0; fb < 4; ++fb){
    int f = fg * 128 + fb * 32 + l31;
    float tcv = T2c[(size_t)qb * 256 + f];
    float ta = 0.f, la = 0.f;
    #pragma unroll
    for (int reg = 0; reg < 16; ++reg){
      int c = c0 + (reg & 3) + 8 * (reg >> 2) + 4 * kh;
      float sv = bflo2f((unsigned int)hsim[(size_t)qb * 131072 + (size_t)c * 256 + f]);
      float e = __expf(sv);
      float v2 = acc[fb][reg] + Mv0T[((size_t)b * 512 + c) * 256 + f] + tcv;
      ta += e * v2;
      la += e;
    }
    tacc[fb] = ta + __shfl_xor(ta, 32, 64);
    lacc[fb] = la + __shfl_xor(la, 32, 64);
  }
  __syncthreads();            // all Wv reads done; alias merge buffers onto Wt
  float* bufT = (float*)Wt;
  float* bufL = bufT + 2048;
  if (l < 32){
    #pragma unroll
    for (int fb = 0; fb < 4; ++fb){
      int f = fg * 128 + fb * 32 + l31;
      bufT[rb * 256 + f] = tacc[fb];
      bufL[rb * 256 + f] = lacc[fb];
    }
  }
  __syncthreads();
  if (tid < 256){
    int f = tid;
    float T = 0.f, L = 0.f;
    #pragma unroll
    for (int r2 = 0; r2 < 8; ++r2){ T += bufT[r2 * 256 + f]; L += bufL[r2 * 256 + f]; }
    partT[((size_t)ch * 512 + qb) * 256 + f] = T;
    partL[((size_t)ch * 512 + qb) * 256 + f] = L;
  }
}

__global__ __launch_bounds__(256) void combine_kernel(
    const float* __restrict__ partT, const float* __restrict__ partL,
    unsigned short* __restrict__ trel)
{
  int i = blockIdx.x * 256 + threadIdx.x;      // 512*256
  float T = partT[i] + partT[131072 + i];
  float L = partL[i] + partL[131072 + i];
  trel[i] = f2bf(T / L);
}

// ---------------------------------------------------------------- launch
extern "C" void kernel_launch(void* const* d_in, const int* in_sizes, int n_in,
                              void* d_out, int out_size, void* d_ws, size_t ws_size,
                              hipStream_t stream)
{
  const float* tgt  = (const float*)d_in[0];
  const float* mem  = (const float*)d_in[1];
  const float* qpos = (const float*)d_in[2];
  const float* rel  = (const float*)d_in[3];
  const float* ln1g = (const float*)d_in[4];
  const float* ln1b = (const float*)d_in[5];
  const float* ln2g = (const float*)d_in[6];
  const float* ln2b = (const float*)d_in[7];
  const float* ln3g = (const float*)d_in[8];
  const float* ln3b = (const float*)d_in[9];
  const float* inw  = (const float*)d_in[10];
  const float* inb  = (const float*)d_in[11];
  const float* aow  = (const float*)d_in[12];
  const float* aob  = (const float*)d_in[13];
  const float* m1w  = (const float*)d_in[14];
  const float* m1b  = (const float*)d_in[15];
  const float* m2w  = (const float*)d_in[16];
  const float* m2b  = (const float*)d_in[17];
  const float* vw   = (const float*)d_in[18];
  const float* vb   = (const float*)d_in[19];
  const float* ow   = (const float*)d_in[20];
  const float* ob   = (const float*)d_in[21];
  const float* f1w  = (const float*)d_in[22];
  const float* f1b  = (const float*)d_in[23];
  const float* f2w  = (const float*)d_in[24];
  const float* f2b  = (const float*)d_in[25];

  char* ws = (char*)d_ws;
  size_t off = 0;
  auto alloc = [&](size_t bytes) -> char* {
    char* p = ws + off; off += (bytes + 255) & ~size_t(255); return p;
  };
  unsigned short* hsim    = (unsigned short*)alloc((size_t)512 * 512 * 256 * 2);   // 134MB
  float*          partT   = (float*)alloc(2 * 512 * 256 * 4);
  float*          partL   = (float*)alloc(2 * 512 * 256 * 4);
  unsigned short* inw_bf  = (unsigned short*)alloc(768 * 256 * 2);
  unsigned short* aow_bf  = (unsigned short*)alloc(256 * 256 * 2);
  unsigned short* ow_bf   = (unsigned short*)alloc(256 * 256 * 2);
  unsigned short* f1w_bf  = (unsigned short*)alloc(1024 * 256 * 2);
  unsigned short* f2w_bf  = (unsigned short*)alloc(256 * 1024 * 2);
  unsigned short* mem_bf  = (unsigned short*)alloc(2048 * 256 * 2);
  unsigned short* vw_bf   = (unsigned short*)alloc(256 * 256 * 2);
  unsigned short* m1w_bf  = (unsigned short*)alloc(256 * 256 * 2);
  unsigned short* m2w_bf  = (unsigned short*)alloc(256 * 256 * 2);
  unsigned short* t21_bf  = (unsigned short*)alloc(512 * 256 * 2);
  unsigned short* qk_bf   = (unsigned short*)alloc(512 * 256 * 2);
  float*          qkp     = (float*)alloc(512 * 512 * 4);
  float*          vp      = (float*)alloc(512 * 256 * 4);
  unsigned short* ao_bf   = (unsigned short*)alloc(512 * 256 * 2);
  float*          tgta    = (float*)alloc(512 * 256 * 4);
  float*          t22_f   = (float*)alloc(512 * 256 * 4);
  unsigned short* t22_bf  = (unsigned short*)alloc(512 * 256 * 2);
  float*          T2c     = (float*)alloc(512 * 256 * 4);
  float*          Mv0T    = (float*)alloc(4 * 512 * 256 * 4);
  unsigned short* trel_bf = (unsigned short*)alloc(512 * 256 * 2);
  float*          tgtr    = (float*)alloc(512 * 256 * 4);
  unsigned short* t23_bf  = (unsigned short*)alloc(512 * 256 * 2);
  unsigned short* ffh_bf  = (unsigned short*)alloc(512 * 1024 * 2);

  conv_lin_kernel<<<2048, 256, 0, stream>>>(inw, inw_bf, aow, aow_bf, ow, ow_bf,
      f1w, f1w_bf, f2w, f2w_bf, mem, mem_bf, vw, vw_bf, m1w, m1w_bf, m2w, m2w_bf);

  // ln1 -> tgt2_1 (bf16), qk = tgt2_1 + query_pos (bf16)
  ln_kernel<<<512, 256, 0, stream>>>(tgt, ln1g, ln1b, qpos, nullptr, t21_bf, qk_bf);

  // q|k projection (N=512) and v projection (N=256)
  gemm_kernel<<<dim3(8, 8), 256, 0, stream>>>(qk_bf, inw_bf, inb, nullptr,
      qkp, nullptr, 512, 512, 256, 1.f, 0, 0);
  gemm_kernel<<<dim3(8, 4), 256, 0, stream>>>(t21_bf, inw_bf + 512 * 256, inb + 512, nullptr,
      vp, nullptr, 512, 256, 256, 1.f, 0, 0);

  attn_kernel<<<32, 256, 0, stream>>>(qkp, vp, ao_bf);

  // out-proj + residual tgt -> tgta
  gemm_kernel<<<dim3(8, 4), 256, 0, stream>>>(ao_bf, aow_bf, aob, tgt,
      tgta, nullptr, 512, 256, 256, 1.f, 0, 0);

  // ln2 -> t22 (f32 + bf16)
  ln_kernel<<<512, 256, 0, stream>>>(tgta, ln2g, ln2b, nullptr, t22_f, t22_bf, nullptr);

  // T2c = vb - tgt2@Wv ; Mv0T[b][c][f] = 2*mem@Wv
  gemm_kernel<<<dim3(8, 4), 256, 0, stream>>>(t22_bf, vw_bf, vb, nullptr,
      T2c, nullptr, 512, 256, 256, -1.f, 0, 0);
  gemm_kernel<<<dim3(32, 4), 256, 0, stream>>>(mem_bf, vw_bf, nullptr, nullptr,
      Mv0T, nullptr, 2048, 256, 256, 2.f, 0, 2);

  // relation branch: 3 streaming passes
  hpass_kernel<<<1024, 1024, 0, stream>>>(rel, mem, t22_f, m1w_bf, m1b, hsim);
  simpass_kernel<<<1024, 1024, 0, stream>>>(m2w_bf, m2b, hsim);
  outpass_kernel<<<1024, 1024, 0, stream>>>(rel, mem, t22_f, vw_bf, hsim,
      Mv0T, T2c, partT, partL);
  combine_kernel<<<512, 256, 0, stream>>>(partT, partL, trel_bf);

  // t = relu(t@o_w + o_b) + t22
  gemm_kernel<<<dim3(8, 4), 256, 0, stream>>>(trel_bf, ow_bf, ob, t22_f,
      tgtr, nullptr, 512, 256, 256, 1.f, 1, 0);

  // ln3 -> bf16
  ln_kernel<<<512, 256, 0, stream>>>(tgtr, ln3g, ln3b, nullptr, nullptr, t23_bf, nullptr);

  // ffn
  gemm_kernel<<<dim3(8, 16), 256, 0, stream>>>(t23_bf, f1w_bf, f1b, nullptr,
      nullptr, ffh_bf, 512, 1024, 256, 1.f, 1, 0);
  gemm_kernel<<<dim3(8, 4), 256, 0, stream>>>(ffh_bf, f2w_bf, f2b, tgtr,
      (float*)d_out, nullptr, 512, 256, 1024, 1.f, 0, 0);
}

// Round 5
// 401.632 us; speedup vs baseline: 2.2782x; 1.6422x over previous
//
#include <hip/hip_runtime.h>
#include <hip/hip_bf16.h>
#include <cstdint>
#include <cstddef>

#define DEV __device__ __forceinline__

typedef __attribute__((ext_vector_type(8))) short short8;
typedef __attribute__((ext_vector_type(4))) float f32x4;

constexpr int Dm  = 256;
constexpr int Qn  = 128;
constexpr int Cn  = 512;
constexpr int Bn  = 4;

DEV unsigned short f2bf(float f){
  unsigned int u = __builtin_bit_cast(unsigned int, f);
  u += 0x7fffu + ((u >> 16) & 1u);
  return (unsigned short)(u >> 16);
}
DEV float bfl(unsigned int u){ return __builtin_bit_cast(float, u << 16); }
DEV float bfh(unsigned int u){ return __builtin_bit_cast(float, u & 0xffff0000u); }
DEV unsigned int pk2(float a, float b){
  return (unsigned int)f2bf(a) | ((unsigned int)f2bf(b) << 16);
}
// y = x + m - t, per packed bf16 pair
DEV unsigned int corr2(unsigned int x, unsigned int m, unsigned int t){
  return pk2(bfl(x) + bfl(m) - bfl(t), bfh(x) + bfh(m) - bfh(t));
}

DEV f32x4 mfma16(short8 a, short8 b, f32x4 c){
  return __builtin_amdgcn_mfma_f32_16x16x32_bf16(a, b, c, 0, 0, 0);
}

// 16x16x32 fragment load from XOR-swizzled LDS tile (rowbytes bytes/row) — for gemm_kernel
DEV short8 ldfrag(const unsigned short* buf, int rowbytes, int row0, int ks, int l){
  int r = row0 + (l & 15);
  int byte = (ks * 64 + ((l >> 4) * 16)) ^ ((r & 7) << 4);
  return *(const short8*)((const char*)buf + r * rowbytes + byte);
}

// async global->LDS, 16B/lane; LDS dest = wave-uniform base (HW adds lane*16)
DEV void gload_lds16(const void* g, void* lds){
  __builtin_amdgcn_global_load_lds(
      (const __attribute__((address_space(1))) unsigned int*)g,
      (__attribute__((address_space(3))) unsigned int*)lds, 16, 0, 0);
}

// ---------------------------------------------------------------- converts + weight packs
// pack W[f][d] into the LDS image: byte f*512 + ((d8*16) ^ ((f&15)<<4)), elem e within chunk
DEV void packw(unsigned short* dst, const float* src, int j){
  int f = j >> 8, d = j & 255;
  int d8 = d >> 3, e = d & 7;
  int byte = (d8 * 16) ^ ((f & 15) << 4);
  dst[f * 256 + (byte >> 1) + e] = f2bf(src[j]);
}

__global__ __launch_bounds__(256) void conv_all_kernel(
    const float* inw, unsigned short* inw_bf,
    const float* aow, unsigned short* aow_bf,
    const float* ow,  unsigned short* ow_bf,
    const float* f1w, unsigned short* f1w_bf,
    const float* f2w, unsigned short* f2w_bf,
    const float* m1w, unsigned short* w1pk,
    const float* m2w, unsigned short* w2pk,
    const float* vw,  unsigned short* wvpk,
    const float* memp, unsigned short* m2r)
{
  const int total = 196608 + 65536 + 65536 + 262144 + 262144 + 3 * 65536 + 524288;
  for (int i = blockIdx.x * 256 + threadIdx.x; i < total; i += gridDim.x * 256){
    int j = i;
    if (j < 196608){ inw_bf[j] = f2bf(inw[j]); continue; } j -= 196608;
    if (j < 65536) { aow_bf[j] = f2bf(aow[j]); continue; } j -= 65536;
    if (j < 65536) { ow_bf[j]  = f2bf(ow[j]);  continue; } j -= 65536;
    if (j < 262144){ f1w_bf[j] = f2bf(f1w[j]); continue; } j -= 262144;
    if (j < 262144){ f2w_bf[j] = f2bf(f2w[j]); continue; } j -= 262144;
    if (j < 65536) { packw(w1pk, m1w, j); continue; } j -= 65536;
    if (j < 65536) { packw(w2pk, m2w, j); continue; } j -= 65536;
    if (j < 65536) { packw(wvpk, vw, j);  continue; } j -= 65536;
    // m2r[b][c][d] = bf16(2*mem[c][b][d])
    int d = j & 255, c = (j >> 8) & 511, b2 = j >> 17;
    m2r[j] = f2bf(2.f * memp[((size_t)c * 4 + b2) * 256 + d]);
  }
}

// ---------------------------------------------------------------- x prepass
// x_sw[qb][c] rows of 512B, chunk d8 stored at byte (d8*16)^((c&15)<<4)
__global__ __launch_bounds__(256) void xprep_kernel(
    const float* __restrict__ rel, const float* __restrict__ memp,
    const float* __restrict__ t22, unsigned short* __restrict__ xg)
{
  const int total = Qn * Cn * Bn * 32;   // 8,388,608 chunks of 8 elems
  for (int i = blockIdx.x * 256 + threadIdx.x; i < total; i += gridDim.x * 256){
    int d8 = i & 31;
    int b  = (i >> 5) & 3;
    int c  = (i >> 7) & 511;
    int q  = i >> 16;
    const float4* rp = (const float4*)(rel + (size_t)i * 8);
    float4 r0 = rp[0], r1 = rp[1];
    const float4* mp = (const float4*)(memp + ((size_t)(c * 4 + b) * 256 + d8 * 8));
    float4 m0 = mp[0], m1 = mp[1];
    const float4* tp = (const float4*)(t22 + ((size_t)(q * 4 + b) * 256 + d8 * 8));
    float4 t0 = tp[0], t1 = tp[1];
    uint4 o;
    o.x = pk2(t0.x - m0.x + r0.x, t0.y - m0.y + r0.y);
    o.y = pk2(t0.z - m0.z + r0.z, t0.w - m0.w + r0.w);
    o.z = pk2(t1.x - m1.x + r1.x, t1.y - m1.y + r1.y);
    o.w = pk2(t1.z - m1.z + r1.z, t1.w - m1.w + r1.w);
    size_t byte = ((size_t)(q * 4 + b) * 512 + c) * 512 + ((d8 * 16) ^ ((c & 15) << 4));
    *(uint4*)((char*)xg + byte) = o;
  }
}

// ---------------------------------------------------------------- layernorm
__global__ __launch_bounds__(256) void ln_kernel(
    const float* __restrict__ in, const float* __restrict__ g, const float* __restrict__ bt,
    const float* __restrict__ addp,
    float* __restrict__ outF, unsigned short* __restrict__ outA, unsigned short* __restrict__ outB)
{
  const int r = blockIdx.x, t = threadIdx.x;
  float x = in[(size_t)r * 256 + t];
  float s = x, s2 = x * x;
  #pragma unroll
  for (int m = 1; m < 64; m <<= 1){ s += __shfl_xor(s, m, 64); s2 += __shfl_xor(s2, m, 64); }
  __shared__ float ls[8];
  int w = t >> 6, l = t & 63;
  if (l == 0){ ls[w] = s; ls[4 + w] = s2; }
  __syncthreads();
  s  = ls[0] + ls[1] + ls[2] + ls[3];
  s2 = ls[4] + ls[5] + ls[6] + ls[7];
  float mean = s * (1.f / 256.f);
  float var  = s2 * (1.f / 256.f) - mean * mean;
  float y = (x - mean) * rsqrtf(var + 1e-5f) * g[t] + bt[t];
  size_t o = (size_t)r * 256 + t;
  if (outF) outF[o] = y;
  if (outA) outA[o] = f2bf(y);
  if (outB) outB[o] = f2bf(y + addp[o]);
}

// ---------------------------------------------------------------- generic GEMM (small mats)
__global__ __launch_bounds__(256, 4) void gemm_kernel(
    const unsigned short* __restrict__ A, const unsigned short* __restrict__ W,
    const float* __restrict__ bias, const float* __restrict__ resid,
    float* __restrict__ Cf, unsigned short* __restrict__ Cb,
    int M, int N, int K, float alpha, int relu)
{
  __shared__ unsigned short As[64 * 64];
  __shared__ unsigned short Ws[64 * 64];
  const int tid = threadIdx.x;
  const int l = tid & 63;
  const int w = tid >> 6;
  const int wm = w >> 1, wn = w & 1;
  const int bm = blockIdx.x * 64, bn = blockIdx.y * 64;
  f32x4 acc[2][2] = {{{0,0,0,0},{0,0,0,0}},{{0,0,0,0},{0,0,0,0}}};

  for (int kc = 0; kc < K; kc += 64){
    __syncthreads();
    #pragma unroll
    for (int i = 0; i < 2; ++i){
      int idx = tid + i * 256;
      int r = idx >> 3, s = idx & 7;
      int byte = (s * 16) ^ ((r & 7) << 4);
      *(short8*)((char*)As + r * 128 + byte) = *(const short8*)(A + (size_t)(bm + r) * K + kc + s * 8);
      *(short8*)((char*)Ws + r * 128 + byte) = *(const short8*)(W + (size_t)(bn + r) * K + kc + s * 8);
    }
    __syncthreads();
    #pragma unroll
    for (int ks = 0; ks < 2; ++ks){
      short8 af[2], bf[2];
      af[0] = ldfrag(As, 128, wm * 32,      ks, l);
      af[1] = ldfrag(As, 128, wm * 32 + 16, ks, l);
      bf[0] = ldfrag(Ws, 128, wn * 32,      ks, l);
      bf[1] = ldfrag(Ws, 128, wn * 32 + 16, ks, l);
      #pragma unroll
      for (int i = 0; i < 2; ++i)
        #pragma unroll
        for (int j = 0; j < 2; ++j)
          acc[i][j] = mfma16(af[i], bf[j], acc[i][j]);
    }
  }
  #pragma unroll
  for (int i = 0; i < 2; ++i)
  #pragma unroll
  for (int j = 0; j < 2; ++j){
    int col = bn + wn * 32 + j * 16 + (l & 15);
    float bv = bias ? bias[col] : 0.f;
    #pragma unroll
    for (int u = 0; u < 4; ++u){
      int row = bm + wm * 32 + i * 16 + ((l >> 4) << 2) + u;
      float v = alpha * acc[i][j][u] + bv;
      if (relu) v = fmaxf(v, 0.f);
      if (resid) v += resid[(size_t)row * N + col];
      if (Cf) Cf[(size_t)row * N + col] = v;
      if (Cb) Cb[(size_t)row * N + col] = f2bf(v);
    }
  }
}

// ---------------------------------------------------------------- self-attention
__global__ __launch_bounds__(256) void attn_kernel(
    const float* __restrict__ qkp, const float* __restrict__ vp,
    unsigned short* __restrict__ attn_o)
{
  __shared__ float ks[128][33];
  __shared__ float vs[128][33];
  __shared__ float sc[128][129];
  const int bh = blockIdx.x;
  const int b = bh >> 3, h = bh & 7;
  const int tid = threadIdx.x;
  const int lrow = tid >> 1;
  const int half = tid & 1;
  {
    int s = tid >> 1;
    int d0 = half * 16;
    const float* kp = qkp + ((size_t)s * Bn + b) * 512 + 256 + h * 32 + d0;
    const float* vv = vp  + ((size_t)s * Bn + b) * 256 +       h * 32 + d0;
    #pragma unroll
    for (int d = 0; d < 16; d += 4){
      *(float4*)&ks[s][d0 + d] = *(const float4*)(kp + d);
      *(float4*)&vs[s][d0 + d] = *(const float4*)(vv + d);
    }
  }
  __syncthreads();
  float qv[32];
  const float* qp = qkp + ((size_t)lrow * Bn + b) * 512 + h * 32;
  #pragma unroll
  for (int d = 0; d < 32; ++d) qv[d] = qp[d];
  const float scale = 0.17677669529663687f;
  float mloc = -1e30f;
  for (int s2 = 0; s2 < 64; ++s2){
    int s = half * 64 + s2;
    float dot = 0.f;
    #pragma unroll
    for (int d = 0; d < 32; ++d) dot += qv[d] * ks[s][d];
    dot *= scale;
    sc[lrow][s] = dot;
    mloc = fmaxf(mloc, dot);
  }
  float m = fmaxf(mloc, __shfl_xor(mloc, 1, 64));
  float sum = 0.f;
  for (int s2 = 0; s2 < 64; ++s2){
    int s = half * 64 + s2;
    float e = __expf(sc[lrow][s] - m);
    sum += e;
    sc[lrow][s] = e;
  }
  sum += __shfl_xor(sum, 1, 64);
  float inv = 1.f / sum;
  float o[32];
  #pragma unroll
  for (int d = 0; d < 32; ++d) o[d] = 0.f;
  for (int s2 = 0; s2 < 64; ++s2){
    int s = half * 64 + s2;
    float e = sc[lrow][s];
    #pragma unroll
    for (int d = 0; d < 32; ++d) o[d] += e * vs[s][d];
  }
  #pragma unroll
  for (int d = 0; d < 32; ++d){
    o[d] += __shfl_xor(o[d], 1, 64);
    o[d] *= inv;
  }
  unsigned short* op = attn_o + ((size_t)lrow * Bn + b) * 256 + h * 32 + half * 16;
  #pragma unroll
  for (int d = 0; d < 16; ++d) op[d] = f2bf(o[half * 16 + d]);
}

// ---------------------------------------------------------------- relation passes
// One block per qb; W (128KB, fragment-packed) LDS-resident; 16-KB input tiles
// (32 c-rows) reg-prefetched (T14) into a single LDS buffer. Swapped-operand MFMA:
// D[f][c] with col c = l&15, row f = lg*4+u (+16j).
// MODE 0: h = relu(x@W1+b1)        -> dst rows [qb][c][f] (swizzled, coalesced 8B)
// MODE 1: sim = (h@W2+b2)/16       -> dst 16B/lane C/D-order dump (in-place over h)
// MODE 2: v2 = y@Wv+vb, y = x+2mem-tgt2 (corr at stage); t=Σe·v2/Σe -> trel[qb][f]
template<int MODE>
__global__ __launch_bounds__(1024, 4) void relpass_kernel(
    const unsigned short* src, const unsigned short* __restrict__ Wg,
    const float* __restrict__ bias, unsigned short* dst,
    const unsigned short* __restrict__ m2r, const unsigned short* __restrict__ t22b,
    const unsigned short* simsrc)
{
  __shared__ unsigned short Wt[65536];   // 128 KB
  __shared__ unsigned short xb[8192];    // 16 KB tile
  const int qb = blockIdx.x;
  const int b = qb & 3;
  const int tid = threadIdx.x;
  const int w = tid >> 6, l = tid & 63;
  const int ch2 = w >> 3, fb = w & 7;
  const int l15 = l & 15, lg = l >> 4;

  // stage W asynchronously (dest = wave-uniform base; HW adds lane*16)
  #pragma unroll
  for (int i = 0; i < 8; ++i){
    int base = w * 64 + i * 1024;
    gload_lds16((const char*)Wg + ((size_t)base + l) * 16, (char*)Wt + (size_t)base * 16);
  }

  const int row = tid >> 5, d8 = tid & 31;
  const int toff = row * 512 + ((d8 * 16) ^ ((row & 15) << 4));
  const char* srcp = (const char*)src + (size_t)qb * 262144;

  uint4 stg = *(const uint4*)(srcp + toff);
  uint4 m2c, t2c;
  if constexpr (MODE == 2){
    m2c = *(const uint4*)((const char*)m2r + ((size_t)(b * 512 + row) * 512) + d8 * 16);
    t2c = *(const uint4*)((const char*)t22b + (size_t)qb * 512 + d8 * 16);
  }
  asm volatile("s_waitcnt vmcnt(0)" ::: "memory");
  if constexpr (MODE == 2){
    stg.x = corr2(stg.x, m2c.x, t2c.x);
    stg.y = corr2(stg.y, m2c.y, t2c.y);
    stg.z = corr2(stg.z, m2c.z, t2c.z);
    stg.w = corr2(stg.w, m2c.w, t2c.w);
  }
  *(uint4*)((char*)xb + toff) = stg;
  __syncthreads();

  float bv[2][4];
  #pragma unroll
  for (int j = 0; j < 2; ++j)
    #pragma unroll
    for (int u = 0; u < 4; ++u)
      bv[j][u] = bias[fb * 32 + j * 16 + lg * 4 + u];

  float ta[2][4], la[2][4];
  if constexpr (MODE == 2){
    #pragma unroll
    for (int j = 0; j < 2; ++j)
      #pragma unroll
      for (int u = 0; u < 4; ++u){ ta[j][u] = 0.f; la[j][u] = 0.f; }
  }

  const int r = ch2 * 16 + l15;
  for (int t = 0; t < 16; ++t){
    // prefetch next tile into regs (latency hides under this tile's MFMAs)
    if (t < 15){
      stg = *(const uint4*)(srcp + (size_t)(t + 1) * 16384 + toff);
      if constexpr (MODE == 2)
        m2c = *(const uint4*)((const char*)m2r + ((size_t)(b * 512 + (t + 1) * 32 + row) * 512) + d8 * 16);
    }
    uint4 simv;
    if constexpr (MODE == 2)
      simv = *(const uint4*)((const char*)simsrc + (size_t)qb * 262144 + (size_t)t * 16384 + (size_t)(w * 64 + l) * 16);

    f32x4 acc[2] = {{0,0,0,0},{0,0,0,0}};
    #pragma unroll
    for (int kc = 0; kc < 8; ++kc){
      short8 bx = *(const short8*)((const char*)xb + r * 512 + ((kc * 64 + lg * 16) ^ ((r & 15) << 4)));
      #pragma unroll
      for (int j = 0; j < 2; ++j){
        int f = fb * 32 + j * 16 + l15;
        short8 aw = *(const short8*)((const char*)Wt + f * 512 + ((kc * 64 + lg * 16) ^ ((f & 15) << 4)));
        acc[j] = mfma16(aw, bx, acc[j]);
      }
    }

    if constexpr (MODE == 0){
      int c = t * 32 + r;
      size_t rowb = (size_t)qb * 262144 + (size_t)c * 512;
      #pragma unroll
      for (int j = 0; j < 2; ++j){
        uint2 pk;
        pk.x = pk2(fmaxf(acc[j][0] + bv[j][0], 0.f), fmaxf(acc[j][1] + bv[j][1], 0.f));
        pk.y = pk2(fmaxf(acc[j][2] + bv[j][2], 0.f), fmaxf(acc[j][3] + bv[j][3], 0.f));
        int inrow = (fb * 64 + j * 32 + lg * 8) ^ ((c & 15) << 4);
        *(uint2*)((char*)dst + rowb + inrow) = pk;
      }
    } else if constexpr (MODE == 1){
      uint4 d;
      d.x = pk2((acc[0][0] + bv[0][0]) * 0.0625f, (acc[0][1] + bv[0][1]) * 0.0625f);
      d.y = pk2((acc[0][2] + bv[0][2]) * 0.0625f, (acc[0][3] + bv[0][3]) * 0.0625f);
      d.z = pk2((acc[1][0] + bv[1][0]) * 0.0625f, (acc[1][1] + bv[1][1]) * 0.0625f);
      d.w = pk2((acc[1][2] + bv[1][2]) * 0.0625f, (acc[1][3] + bv[1][3]) * 0.0625f);
      *(uint4*)((char*)dst + (size_t)qb * 262144 + (size_t)t * 16384 + (size_t)(w * 64 + l) * 16) = d;
    } else {
      const unsigned int sv[4] = {simv.x, simv.y, simv.z, simv.w};
      #pragma unroll
      for (int j = 0; j < 2; ++j)
        #pragma unroll
        for (int p = 0; p < 2; ++p){
          unsigned int s2 = sv[j * 2 + p];
          float e0 = __expf(bfl(s2)), e1 = __expf(bfh(s2));
          float v0 = acc[j][p * 2 + 0] + bv[j][p * 2 + 0];
          float v1 = acc[j][p * 2 + 1] + bv[j][p * 2 + 1];
          ta[j][p * 2 + 0] += e0 * v0;  la[j][p * 2 + 0] += e0;
          ta[j][p * 2 + 1] += e1 * v1;  la[j][p * 2 + 1] += e1;
        }
    }

    if (t < 15){
      __syncthreads();                  // all xb reads done
      if constexpr (MODE == 2){
        stg.x = corr2(stg.x, m2c.x, t2c.x);
        stg.y = corr2(stg.y, m2c.y, t2c.y);
        stg.z = corr2(stg.z, m2c.z, t2c.z);
        stg.w = corr2(stg.w, m2c.w, t2c.w);
      }
      *(uint4*)((char*)xb + toff) = stg;
      __syncthreads();
    }
  }

  if constexpr (MODE == 2){
    #pragma unroll
    for (int j = 0; j < 2; ++j)
      #pragma unroll
      for (int u = 0; u < 4; ++u){
        #pragma unroll
        for (int m = 1; m <= 8; m <<= 1){
          ta[j][u] += __shfl_xor(ta[j][u], m, 64);
          la[j][u] += __shfl_xor(la[j][u], m, 64);
        }
      }
    __syncthreads();
    float* bufT = (float*)xb;
    float* bufL = bufT + 512;
    if (l15 == 0){
      #pragma unroll
      for (int j = 0; j < 2; ++j)
        #pragma unroll
        for (int u = 0; u < 4; ++u){
          int f = fb * 32 + j * 16 + lg * 4 + u;
          bufT[ch2 * 256 + f] = ta[j][u];
          bufL[ch2 * 256 + f] = la[j][u];
        }
    }
    __syncthreads();
    if (tid < 256){
      float T = bufT[tid] + bufT[256 + tid];
      float L = bufL[tid] + bufL[256 + tid];
      dst[(size_t)qb * 256 + tid] = f2bf(T / L);
    }
  }
}

// ---------------------------------------------------------------- launch
extern "C" void kernel_launch(void* const* d_in, const int* in_sizes, int n_in,
                              void* d_out, int out_size, void* d_ws, size_t ws_size,
                              hipStream_t stream)
{
  const float* tgt  = (const float*)d_in[0];
  const float* mem  = (const float*)d_in[1];
  const float* qpos = (const float*)d_in[2];
  const float* rel  = (const float*)d_in[3];
  const float* ln1g = (const float*)d_in[4];
  const float* ln1b = (const float*)d_in[5];
  const float* ln2g = (const float*)d_in[6];
  const float* ln2b = (const float*)d_in[7];
  const float* ln3g = (const float*)d_in[8];
  const float* ln3b = (const float*)d_in[9];
  const float* inw  = (const float*)d_in[10];
  const float* inb  = (const float*)d_in[11];
  const float* aow  = (const float*)d_in[12];
  const float* aob  = (const float*)d_in[13];
  const float* m1w  = (const float*)d_in[14];
  const float* m1b  = (const float*)d_in[15];
  const float* m2w  = (const float*)d_in[16];
  const float* m2b  = (const float*)d_in[17];
  const float* vw   = (const float*)d_in[18];
  const float* vb   = (const float*)d_in[19];
  const float* ow   = (const float*)d_in[20];
  const float* ob   = (const float*)d_in[21];
  const float* f1w  = (const float*)d_in[22];
  const float* f1b  = (const float*)d_in[23];
  const float* f2w  = (const float*)d_in[24];
  const float* f2b  = (const float*)d_in[25];

  char* ws = (char*)d_ws;
  size_t off = 0;
  auto alloc = [&](size_t bytes) -> char* {
    char* p = ws + off; off += (bytes + 255) & ~size_t(255); return p;
  };
  unsigned short* x_sw    = (unsigned short*)alloc((size_t)512 * 512 * 256 * 2);  // 134 MB
  unsigned short* h_sw    = (unsigned short*)alloc((size_t)512 * 512 * 256 * 2);  // 134 MB (h, then sim)
  unsigned short* m2r     = (unsigned short*)alloc(4 * 512 * 256 * 2);            // 1 MB
  unsigned short* w1pk    = (unsigned short*)alloc(256 * 256 * 2);
  unsigned short* w2pk    = (unsigned short*)alloc(256 * 256 * 2);
  unsigned short* wvpk    = (unsigned short*)alloc(256 * 256 * 2);
  unsigned short* inw_bf  = (unsigned short*)alloc(768 * 256 * 2);
  unsigned short* aow_bf  = (unsigned short*)alloc(256 * 256 * 2);
  unsigned short* ow_bf   = (unsigned short*)alloc(256 * 256 * 2);
  unsigned short* f1w_bf  = (unsigned short*)alloc(1024 * 256 * 2);
  unsigned short* f2w_bf  = (unsigned short*)alloc(256 * 1024 * 2);
  unsigned short* t21_bf  = (unsigned short*)alloc(512 * 256 * 2);
  unsigned short* qk_bf   = (unsigned short*)alloc(512 * 256 * 2);
  float*          qkp     = (float*)alloc(512 * 512 * 4);
  float*          vp      = (float*)alloc(512 * 256 * 4);
  unsigned short* ao_bf   = (unsigned short*)alloc(512 * 256 * 2);
  float*          tgta    = (float*)alloc(512 * 256 * 4);
  float*          t22_f   = (float*)alloc(512 * 256 * 4);
  unsigned short* t22_bf  = (unsigned short*)alloc(512 * 256 * 2);
  unsigned short* trel_bf = (unsigned short*)alloc(512 * 256 * 2);
  float*          tgtr    = (float*)alloc(512 * 256 * 4);
  unsigned short* t23_bf  = (unsigned short*)alloc(512 * 256 * 2);
  unsigned short* ffh_bf  = (unsigned short*)alloc(512 * 1024 * 2);

  conv_all_kernel<<<2048, 256, 0, stream>>>(inw, inw_bf, aow, aow_bf, ow, ow_bf,
      f1w, f1w_bf, f2w, f2w_bf, m1w, w1pk, m2w, w2pk, vw, wvpk, mem, m2r);

  // ln1 -> tgt2_1 (bf16), qk = tgt2_1 + query_pos (bf16)
  ln_kernel<<<512, 256, 0, stream>>>(tgt, ln1g, ln1b, qpos, nullptr, t21_bf, qk_bf);

  // q|k projection (N=512) and v projection (N=256)
  gemm_kernel<<<dim3(8, 8), 256, 0, stream>>>(qk_bf, inw_bf, inb, nullptr,
      qkp, nullptr, 512, 512, 256, 1.f, 0);
  gemm_kernel<<<dim3(8, 4), 256, 0, stream>>>(t21_bf, inw_bf + 512 * 256, inb + 512, nullptr,
      vp, nullptr, 512, 256, 256, 1.f, 0);

  attn_kernel<<<32, 256, 0, stream>>>(qkp, vp, ao_bf);

  // out-proj + residual tgt -> tgta
  gemm_kernel<<<dim3(8, 4), 256, 0, stream>>>(ao_bf, aow_bf, aob, tgt,
      tgta, nullptr, 512, 256, 256, 1.f, 0);

  // ln2 -> t22 (f32 + bf16)
  ln_kernel<<<512, 256, 0, stream>>>(tgta, ln2g, ln2b, nullptr, t22_f, t22_bf, nullptr);

  // x = bf16(tgt2 - mem + rel), tile-swizzled
  xprep_kernel<<<2048, 256, 0, stream>>>(rel, mem, t22_f, x_sw);

  // relation: h -> sim (in-place dump) -> weighted sum
  relpass_kernel<0><<<512, 1024, 0, stream>>>(x_sw, w1pk, m1b, h_sw, nullptr, nullptr, nullptr);
  relpass_kernel<1><<<512, 1024, 0, stream>>>(h_sw, w2pk, m2b, h_sw, nullptr, nullptr, nullptr);
  relpass_kernel<2><<<512, 1024, 0, stream>>>(x_sw, wvpk, vb, trel_bf, m2r, t22_bf, h_sw);

  // t = relu(t@o_w + o_b) + t22
  gemm_kernel<<<dim3(8, 4), 256, 0, stream>>>(trel_bf, ow_bf, ob, t22_f,
      tgtr, nullptr, 512, 256, 256, 1.f, 1);

  // ln3 -> bf16
  ln_kernel<<<512, 256, 0, stream>>>(tgtr, ln3g, ln3b, nullptr, nullptr, t23_bf, nullptr);

  // ffn
  gemm_kernel<<<dim3(8, 16), 256, 0, stream>>>(t23_bf, f1w_bf, f1b, nullptr,
      nullptr, ffh_bf, 512, 1024, 256, 1.f, 1);
  gemm_kernel<<<dim3(8, 4), 256, 0, stream>>>(ffh_bf, f2w_bf, f2b, tgtr,
      (float*)d_out, nullptr, 512, 256, 1024, 1.f, 0);
}

// Round 6
// 373.317 us; speedup vs baseline: 2.4509x; 1.0758x over previous
//
#include <hip/hip_runtime.h>
#include <hip/hip_bf16.h>
#include <cstdint>
#include <cstddef>

#define DEV __device__ __forceinline__

typedef __attribute__((ext_vector_type(8))) short short8;
typedef __attribute__((ext_vector_type(4))) float f32x4;

constexpr int Dm  = 256;
constexpr int Qn  = 128;
constexpr int Cn  = 512;
constexpr int Bn  = 4;

DEV unsigned short f2bf(float f){
  unsigned int u = __builtin_bit_cast(unsigned int, f);
  u += 0x7fffu + ((u >> 16) & 1u);
  return (unsigned short)(u >> 16);
}
DEV float bfl(unsigned int u){ return __builtin_bit_cast(float, u << 16); }
DEV float bfh(unsigned int u){ return __builtin_bit_cast(float, u & 0xffff0000u); }
DEV unsigned int pk2(float a, float b){
  return (unsigned int)f2bf(a) | ((unsigned int)f2bf(b) << 16);
}

DEV f32x4 mfma16(short8 a, short8 b, f32x4 c){
  return __builtin_amdgcn_mfma_f32_16x16x32_bf16(a, b, c, 0, 0, 0);
}

// 16x16x32 fragment load from XOR-swizzled LDS tile (rowbytes bytes/row) — for gemm_kernel
DEV short8 ldfrag(const unsigned short* buf, int rowbytes, int row0, int ks, int l){
  int r = row0 + (l & 15);
  int byte = (ks * 64 + ((l >> 4) * 16)) ^ ((r & 7) << 4);
  return *(const short8*)((const char*)buf + r * rowbytes + byte);
}

// async global->LDS, 16B/lane; LDS dest = wave-uniform base (HW adds lane*16)
DEV void gload_lds16(const void* g, void* lds){
  __builtin_amdgcn_global_load_lds(
      (const __attribute__((address_space(1))) unsigned int*)g,
      (__attribute__((address_space(3))) unsigned int*)lds, 16, 0, 0);
}

// ---------------------------------------------------------------- converts + weight packs
// pack W[f][d] into the LDS image: byte f*512 + ((d8*16) ^ ((f&15)<<4)), elem e within chunk
DEV void packw(unsigned short* dst, const float* src, int j){
  int f = j >> 8, d = j & 255;
  int d8 = d >> 3, e = d & 7;
  int byte = (d8 * 16) ^ ((f & 15) << 4);
  dst[f * 256 + (byte >> 1) + e] = f2bf(src[j]);
}

__global__ __launch_bounds__(256) void conv_all_kernel(
    const float* inw, unsigned short* inw_bf,
    const float* aow, unsigned short* aow_bf,
    const float* ow,  unsigned short* ow_bf,
    const float* f1w, unsigned short* f1w_bf,
    const float* f2w, unsigned short* f2w_bf,
    const float* m1w, unsigned short* w1pk,
    const float* m2w, unsigned short* w2pk,
    const float* vw,  unsigned short* wvpk)
{
  const int total = 196608 + 65536 + 65536 + 262144 + 262144 + 3 * 65536;
  for (int i = blockIdx.x * 256 + threadIdx.x; i < total; i += gridDim.x * 256){
    int j = i;
    if (j < 196608){ inw_bf[j] = f2bf(inw[j]); continue; } j -= 196608;
    if (j < 65536) { aow_bf[j] = f2bf(aow[j]); continue; } j -= 65536;
    if (j < 65536) { ow_bf[j]  = f2bf(ow[j]);  continue; } j -= 65536;
    if (j < 262144){ f1w_bf[j] = f2bf(f1w[j]); continue; } j -= 262144;
    if (j < 262144){ f2w_bf[j] = f2bf(f2w[j]); continue; } j -= 262144;
    if (j < 65536) { packw(w1pk, m1w, j); continue; } j -= 65536;
    if (j < 65536) { packw(w2pk, m2w, j); continue; } j -= 65536;
    packw(wvpk, vw, j);
  }
}

// ---------------------------------------------------------------- layernorm
__global__ __launch_bounds__(256) void ln_kernel(
    const float* __restrict__ in, const float* __restrict__ g, const float* __restrict__ bt,
    const float* __restrict__ addp,
    float* __restrict__ outF, unsigned short* __restrict__ outA, unsigned short* __restrict__ outB)
{
  const int r = blockIdx.x, t = threadIdx.x;
  float x = in[(size_t)r * 256 + t];
  float s = x, s2 = x * x;
  #pragma unroll
  for (int m = 1; m < 64; m <<= 1){ s += __shfl_xor(s, m, 64); s2 += __shfl_xor(s2, m, 64); }
  __shared__ float ls[8];
  int w = t >> 6, l = t & 63;
  if (l == 0){ ls[w] = s; ls[4 + w] = s2; }
  __syncthreads();
  s  = ls[0] + ls[1] + ls[2] + ls[3];
  s2 = ls[4] + ls[5] + ls[6] + ls[7];
  float mean = s * (1.f / 256.f);
  float var  = s2 * (1.f / 256.f) - mean * mean;
  float y = (x - mean) * rsqrtf(var + 1e-5f) * g[t] + bt[t];
  size_t o = (size_t)r * 256 + t;
  if (outF) outF[o] = y;
  if (outA) outA[o] = f2bf(y);
  if (outB) outB[o] = f2bf(y + addp[o]);
}

// ---------------------------------------------------------------- generic GEMM (small mats)
__global__ __launch_bounds__(256, 4) void gemm_kernel(
    const unsigned short* __restrict__ A, const unsigned short* __restrict__ W,
    const float* __restrict__ bias, const float* __restrict__ resid,
    float* __restrict__ Cf, unsigned short* __restrict__ Cb,
    int M, int N, int K, float alpha, int relu)
{
  __shared__ unsigned short As[64 * 64];
  __shared__ unsigned short Ws[64 * 64];
  const int tid = threadIdx.x;
  const int l = tid & 63;
  const int w = tid >> 6;
  const int wm = w >> 1, wn = w & 1;
  const int bm = blockIdx.x * 64, bn = blockIdx.y * 64;
  f32x4 acc[2][2] = {{{0,0,0,0},{0,0,0,0}},{{0,0,0,0},{0,0,0,0}}};

  for (int kc = 0; kc < K; kc += 64){
    __syncthreads();
    #pragma unroll
    for (int i = 0; i < 2; ++i){
      int idx = tid + i * 256;
      int r = idx >> 3, s = idx & 7;
      int byte = (s * 16) ^ ((r & 7) << 4);
      *(short8*)((char*)As + r * 128 + byte) = *(const short8*)(A + (size_t)(bm + r) * K + kc + s * 8);
      *(short8*)((char*)Ws + r * 128 + byte) = *(const short8*)(W + (size_t)(bn + r) * K + kc + s * 8);
    }
    __syncthreads();
    #pragma unroll
    for (int ks = 0; ks < 2; ++ks){
      short8 af[2], bf[2];
      af[0] = ldfrag(As, 128, wm * 32,      ks, l);
      af[1] = ldfrag(As, 128, wm * 32 + 16, ks, l);
      bf[0] = ldfrag(Ws, 128, wn * 32,      ks, l);
      bf[1] = ldfrag(Ws, 128, wn * 32 + 16, ks, l);
      #pragma unroll
      for (int i = 0; i < 2; ++i)
        #pragma unroll
        for (int j = 0; j < 2; ++j)
          acc[i][j] = mfma16(af[i], bf[j], acc[i][j]);
    }
  }
  #pragma unroll
  for (int i = 0; i < 2; ++i)
  #pragma unroll
  for (int j = 0; j < 2; ++j){
    int col = bn + wn * 32 + j * 16 + (l & 15);
    float bv = bias ? bias[col] : 0.f;
    #pragma unroll
    for (int u = 0; u < 4; ++u){
      int row = bm + wm * 32 + i * 16 + ((l >> 4) << 2) + u;
      float v = alpha * acc[i][j][u] + bv;
      if (relu) v = fmaxf(v, 0.f);
      if (resid) v += resid[(size_t)row * N + col];
      if (Cf) Cf[(size_t)row * N + col] = v;
      if (Cb) Cb[(size_t)row * N + col] = f2bf(v);
    }
  }
}

// ---------------------------------------------------------------- self-attention
__global__ __launch_bounds__(256) void attn_kernel(
    const float* __restrict__ qkp, const float* __restrict__ vp,
    unsigned short* __restrict__ attn_o)
{
  __shared__ float ks[128][33];
  __shared__ float vs[128][33];
  __shared__ float sc[128][129];
  const int bh = blockIdx.x;
  const int b = bh >> 3, h = bh & 7;
  const int tid = threadIdx.x;
  const int lrow = tid >> 1;
  const int half = tid & 1;
  {
    int s = tid >> 1;
    int d0 = half * 16;
    const float* kp = qkp + ((size_t)s * Bn + b) * 512 + 256 + h * 32 + d0;
    const float* vv = vp  + ((size_t)s * Bn + b) * 256 +       h * 32 + d0;
    #pragma unroll
    for (int d = 0; d < 16; d += 4){
      *(float4*)&ks[s][d0 + d] = *(const float4*)(kp + d);
      *(float4*)&vs[s][d0 + d] = *(const float4*)(vv + d);
    }
  }
  __syncthreads();
  float qv[32];
  const float* qp = qkp + ((size_t)lrow * Bn + b) * 512 + h * 32;
  #pragma unroll
  for (int d = 0; d < 32; ++d) qv[d] = qp[d];
  const float scale = 0.17677669529663687f;
  float mloc = -1e30f;
  for (int s2 = 0; s2 < 64; ++s2){
    int s = half * 64 + s2;
    float dot = 0.f;
    #pragma unroll
    for (int d = 0; d < 32; ++d) dot += qv[d] * ks[s][d];
    dot *= scale;
    sc[lrow][s] = dot;
    mloc = fmaxf(mloc, dot);
  }
  float m = fmaxf(mloc, __shfl_xor(mloc, 1, 64));
  float sum = 0.f;
  for (int s2 = 0; s2 < 64; ++s2){
    int s = half * 64 + s2;
    float e = __expf(sc[lrow][s] - m);
    sum += e;
    sc[lrow][s] = e;
  }
  sum += __shfl_xor(sum, 1, 64);
  float inv = 1.f / sum;
  float o[32];
  #pragma unroll
  for (int d = 0; d < 32; ++d) o[d] = 0.f;
  for (int s2 = 0; s2 < 64; ++s2){
    int s = half * 64 + s2;
    float e = sc[lrow][s];
    #pragma unroll
    for (int d = 0; d < 32; ++d) o[d] += e * vs[s][d];
  }
  #pragma unroll
  for (int d = 0; d < 32; ++d){
    o[d] += __shfl_xor(o[d], 1, 64);
    o[d] *= inv;
  }
  unsigned short* op = attn_o + ((size_t)lrow * Bn + b) * 256 + h * 32 + half * 16;
  #pragma unroll
  for (int d = 0; d < 16; ++d) op[d] = f2bf(o[half * 16 + d]);
}

// ---------------------------------------------------------------- relation passes
// One block per qb; W (128KB, fragment-packed) LDS-resident; 16-KB c-tiles
// (32 rows) reg-prefetched into a single LDS buffer. Swapped-operand MFMA:
// D[f][c], col c = l&15, row f = lg*4+u (+16j).
// MODE 0: reads rel f32, builds x = t22-mem+rel (LDS) and y = rel+mem (-> ydst bf16);
//         h = relu(x@W1+b1) -> dst rows [qb][c][f] (swizzled)
// MODE 1: sim = (h@W2+b2)/16 -> dst 16B/lane C/D-order dump (in-place over h)
// MODE 2: v2 = y@Wv+vb; t = Σ exp(sim)·v2 / Σ exp(sim) -> dst trel[qb][f]
template<int MODE>
__global__ __launch_bounds__(1024, 4) void relpass_kernel(
    const float* __restrict__ rel, const float* __restrict__ memp,
    const float* __restrict__ t22f,
    const unsigned short* src, const unsigned short* __restrict__ Wg,
    const float* __restrict__ bias, unsigned short* dst,
    unsigned short* ydst, const unsigned short* __restrict__ simsrc)
{
  __shared__ unsigned short Wt[65536];   // 128 KB
  __shared__ unsigned short xb[8192];    // 16 KB tile
  const int qb = blockIdx.x;
  const int q = qb >> 2, b = qb & 3;
  const int tid = threadIdx.x;
  const int w = tid >> 6, l = tid & 63;
  const int ch2 = w >> 3, fb = w & 7;
  const int l15 = l & 15, lg = l >> 4;

  // stage W asynchronously (dest = wave-uniform base; HW adds lane*16)
  #pragma unroll
  for (int i = 0; i < 8; ++i){
    int base = w * 64 + i * 1024;
    gload_lds16((const char*)Wg + ((size_t)base + l) * 16, (char*)Wt + (size_t)base * 16);
  }

  const int row = tid >> 5, d8 = tid & 31;
  const int toff = row * 512 + ((d8 * 16) ^ ((row & 15) << 4));
  const char* srcp = (const char*)src + (size_t)qb * 262144;

  float4 t20, t21;
  float4 r0, r1, m0, m1;
  uint4 stg;
  if constexpr (MODE == 0){
    t20 = *(const float4*)(t22f + (size_t)qb * 256 + d8 * 8);
    t21 = *(const float4*)(t22f + (size_t)qb * 256 + d8 * 8 + 4);
    const float* rp = rel + (((size_t)q * 512 + row) * 4 + b) * 256 + d8 * 8;
    const float* mp = memp + ((size_t)(row * 4 + b)) * 256 + d8 * 8;
    r0 = *(const float4*)rp;  r1 = *(const float4*)(rp + 4);
    m0 = *(const float4*)mp;  m1 = *(const float4*)(mp + 4);
  } else {
    stg = *(const uint4*)(srcp + toff);
  }
  asm volatile("s_waitcnt vmcnt(0)" ::: "memory");
  if constexpr (MODE == 0){
    uint4 xw, yw;
    xw.x = pk2(t20.x - m0.x + r0.x, t20.y - m0.y + r0.y);
    xw.y = pk2(t20.z - m0.z + r0.z, t20.w - m0.w + r0.w);
    xw.z = pk2(t21.x - m1.x + r1.x, t21.y - m1.y + r1.y);
    xw.w = pk2(t21.z - m1.z + r1.z, t21.w - m1.w + r1.w);
    yw.x = pk2(r0.x + m0.x, r0.y + m0.y);
    yw.y = pk2(r0.z + m0.z, r0.w + m0.w);
    yw.z = pk2(r1.x + m1.x, r1.y + m1.y);
    yw.w = pk2(r1.z + m1.z, r1.w + m1.w);
    *(uint4*)((char*)ydst + (size_t)qb * 262144 + toff) = yw;
    *(uint4*)((char*)xb + toff) = xw;
  } else {
    *(uint4*)((char*)xb + toff) = stg;
  }
  __syncthreads();

  float bv[2][4];
  #pragma unroll
  for (int j = 0; j < 2; ++j)
    #pragma unroll
    for (int u = 0; u < 4; ++u)
      bv[j][u] = bias[fb * 32 + j * 16 + lg * 4 + u];

  float ta[2][4], la[2][4];
  if constexpr (MODE == 2){
    #pragma unroll
    for (int j = 0; j < 2; ++j)
      #pragma unroll
      for (int u = 0; u < 4; ++u){ ta[j][u] = 0.f; la[j][u] = 0.f; }
  }

  const int r = ch2 * 16 + l15;
  for (int t = 0; t < 16; ++t){
    // prefetch next tile (latency hides under this tile's MFMAs)
    if (t < 15){
      if constexpr (MODE == 0){
        int c = (t + 1) * 32 + row;
        const float* rp = rel + (((size_t)q * 512 + c) * 4 + b) * 256 + d8 * 8;
        const float* mp = memp + ((size_t)(c * 4 + b)) * 256 + d8 * 8;
        r0 = *(const float4*)rp;  r1 = *(const float4*)(rp + 4);
        m0 = *(const float4*)mp;  m1 = *(const float4*)(mp + 4);
      } else {
        stg = *(const uint4*)(srcp + (size_t)(t + 1) * 16384 + toff);
      }
    }
    uint4 simv;
    if constexpr (MODE == 2)
      simv = *(const uint4*)((const char*)simsrc + (size_t)qb * 262144 + (size_t)t * 16384 + (size_t)(w * 64 + l) * 16);

    f32x4 acc[2] = {{0,0,0,0},{0,0,0,0}};
    #pragma unroll
    for (int kc = 0; kc < 8; ++kc){
      short8 bx = *(const short8*)((const char*)xb + r * 512 + ((kc * 64 + lg * 16) ^ ((r & 15) << 4)));
      #pragma unroll
      for (int j = 0; j < 2; ++j){
        int f = fb * 32 + j * 16 + l15;
        short8 aw = *(const short8*)((const char*)Wt + f * 512 + ((kc * 64 + lg * 16) ^ ((f & 15) << 4)));
        acc[j] = mfma16(aw, bx, acc[j]);
      }
    }

    if constexpr (MODE == 0){
      int c = t * 32 + r;
      size_t rowb = (size_t)qb * 262144 + (size_t)c * 512;
      #pragma unroll
      for (int j = 0; j < 2; ++j){
        uint2 pk;
        pk.x = pk2(fmaxf(acc[j][0] + bv[j][0], 0.f), fmaxf(acc[j][1] + bv[j][1], 0.f));
        pk.y = pk2(fmaxf(acc[j][2] + bv[j][2], 0.f), fmaxf(acc[j][3] + bv[j][3], 0.f));
        int inrow = (fb * 64 + j * 32 + lg * 8) ^ ((c & 15) << 4);
        *(uint2*)((char*)dst + rowb + inrow) = pk;
      }
    } else if constexpr (MODE == 1){
      uint4 d;
      d.x = pk2((acc[0][0] + bv[0][0]) * 0.0625f, (acc[0][1] + bv[0][1]) * 0.0625f);
      d.y = pk2((acc[0][2] + bv[0][2]) * 0.0625f, (acc[0][3] + bv[0][3]) * 0.0625f);
      d.z = pk2((acc[1][0] + bv[1][0]) * 0.0625f, (acc[1][1] + bv[1][1]) * 0.0625f);
      d.w = pk2((acc[1][2] + bv[1][2]) * 0.0625f, (acc[1][3] + bv[1][3]) * 0.0625f);
      *(uint4*)((char*)dst + (size_t)qb * 262144 + (size_t)t * 16384 + (size_t)(w * 64 + l) * 16) = d;
    } else {
      const unsigned int sv[4] = {simv.x, simv.y, simv.z, simv.w};
      #pragma unroll
      for (int j = 0; j < 2; ++j)
        #pragma unroll
        for (int p = 0; p < 2; ++p){
          unsigned int s2 = sv[j * 2 + p];
          float e0 = __expf(bfl(s2)), e1 = __expf(bfh(s2));
          float v0 = acc[j][p * 2 + 0] + bv[j][p * 2 + 0];
          float v1 = acc[j][p * 2 + 1] + bv[j][p * 2 + 1];
          ta[j][p * 2 + 0] += e0 * v0;  la[j][p * 2 + 0] += e0;
          ta[j][p * 2 + 1] += e1 * v1;  la[j][p * 2 + 1] += e1;
        }
    }

    if (t < 15){
      __syncthreads();                  // all xb reads done
      if constexpr (MODE == 0){
        uint4 xw, yw;
        xw.x = pk2(t20.x - m0.x + r0.x, t20.y - m0.y + r0.y);
        xw.y = pk2(t20.z - m0.z + r0.z, t20.w - m0.w + r0.w);
        xw.z = pk2(t21.x - m1.x + r1.x, t21.y - m1.y + r1.y);
        xw.w = pk2(t21.z - m1.z + r1.z, t21.w - m1.w + r1.w);
        yw.x = pk2(r0.x + m0.x, r0.y + m0.y);
        yw.y = pk2(r0.z + m0.z, r0.w + m0.w);
        yw.z = pk2(r1.x + m1.x, r1.y + m1.y);
        yw.w = pk2(r1.z + m1.z, r1.w + m1.w);
        *(uint4*)((char*)ydst + (size_t)qb * 262144 + (size_t)(t + 1) * 16384 + toff) = yw;
        *(uint4*)((char*)xb + toff) = xw;
      } else {
        *(uint4*)((char*)xb + toff) = stg;
      }
      __syncthreads();
    }
  }

  if constexpr (MODE == 2){
    #pragma unroll
    for (int j = 0; j < 2; ++j)
      #pragma unroll
      for (int u = 0; u < 4; ++u){
        #pragma unroll
        for (int m = 1; m <= 8; m <<= 1){
          ta[j][u] += __shfl_xor(ta[j][u], m, 64);
          la[j][u] += __shfl_xor(la[j][u], m, 64);
        }
      }
    __syncthreads();
    float* bufT = (float*)xb;
    float* bufL = bufT + 512;
    if (l15 == 0){
      #pragma unroll
      for (int j = 0; j < 2; ++j)
        #pragma unroll
        for (int u = 0; u < 4; ++u){
          int f = fb * 32 + j * 16 + lg * 4 + u;
          bufT[ch2 * 256 + f] = ta[j][u];
          bufL[ch2 * 256 + f] = la[j][u];
        }
    }
    __syncthreads();
    if (tid < 256){
      float T = bufT[tid] + bufT[256 + tid];
      float L = bufL[tid] + bufL[256 + tid];
      dst[(size_t)qb * 256 + tid] = f2bf(T / L);
    }
  }
}

// ---------------------------------------------------------------- launch
extern "C" void kernel_launch(void* const* d_in, const int* in_sizes, int n_in,
                              void* d_out, int out_size, void* d_ws, size_t ws_size,
                              hipStream_t stream)
{
  const float* tgt  = (const float*)d_in[0];
  const float* mem  = (const float*)d_in[1];
  const float* qpos = (const float*)d_in[2];
  const float* rel  = (const float*)d_in[3];
  const float* ln1g = (const float*)d_in[4];
  const float* ln1b = (const float*)d_in[5];
  const float* ln2g = (const float*)d_in[6];
  const float* ln2b = (const float*)d_in[7];
  const float* ln3g = (const float*)d_in[8];
  const float* ln3b = (const float*)d_in[9];
  const float* inw  = (const float*)d_in[10];
  const float* inb  = (const float*)d_in[11];
  const float* aow  = (const float*)d_in[12];
  const float* aob  = (const float*)d_in[13];
  const float* m1w  = (const float*)d_in[14];
  const float* m1b  = (const float*)d_in[15];
  const float* m2w  = (const float*)d_in[16];
  const float* m2b  = (const float*)d_in[17];
  const float* vw   = (const float*)d_in[18];
  const float* vb   = (const float*)d_in[19];
  const float* ow   = (const float*)d_in[20];
  const float* ob   = (const float*)d_in[21];
  const float* f1w  = (const float*)d_in[22];
  const float* f1b  = (const float*)d_in[23];
  const float* f2w  = (const float*)d_in[24];
  const float* f2b  = (const float*)d_in[25];

  char* ws = (char*)d_ws;
  size_t off = 0;
  auto alloc = [&](size_t bytes) -> char* {
    char* p = ws + off; off += (bytes + 255) & ~size_t(255); return p;
  };
  unsigned short* y_sw    = (unsigned short*)alloc((size_t)512 * 512 * 256 * 2);  // 134 MB
  unsigned short* h_sw    = (unsigned short*)alloc((size_t)512 * 512 * 256 * 2);  // 134 MB (h, then sim)
  unsigned short* w1pk    = (unsigned short*)alloc(256 * 256 * 2);
  unsigned short* w2pk    = (unsigned short*)alloc(256 * 256 * 2);
  unsigned short* wvpk    = (unsigned short*)alloc(256 * 256 * 2);
  unsigned short* inw_bf  = (unsigned short*)alloc(768 * 256 * 2);
  unsigned short* aow_bf  = (unsigned short*)alloc(256 * 256 * 2);
  unsigned short* ow_bf   = (unsigned short*)alloc(256 * 256 * 2);
  unsigned short* f1w_bf  = (unsigned short*)alloc(1024 * 256 * 2);
  unsigned short* f2w_bf  = (unsigned short*)alloc(256 * 1024 * 2);
  unsigned short* t21_bf  = (unsigned short*)alloc(512 * 256 * 2);
  unsigned short* qk_bf   = (unsigned short*)alloc(512 * 256 * 2);
  float*          qkp     = (float*)alloc(512 * 512 * 4);
  float*          vp      = (float*)alloc(512 * 256 * 4);
  unsigned short* ao_bf   = (unsigned short*)alloc(512 * 256 * 2);
  float*          tgta    = (float*)alloc(512 * 256 * 4);
  float*          t22_f   = (float*)alloc(512 * 256 * 4);
  unsigned short* trel_bf = (unsigned short*)alloc(512 * 256 * 2);
  float*          tgtr    = (float*)alloc(512 * 256 * 4);
  unsigned short* t23_bf  = (unsigned short*)alloc(512 * 256 * 2);
  unsigned short* ffh_bf  = (unsigned short*)alloc(512 * 1024 * 2);

  conv_all_kernel<<<2048, 256, 0, stream>>>(inw, inw_bf, aow, aow_bf, ow, ow_bf,
      f1w, f1w_bf, f2w, f2w_bf, m1w, w1pk, m2w, w2pk, vw, wvpk);

  // ln1 -> tgt2_1 (bf16), qk = tgt2_1 + query_pos (bf16)
  ln_kernel<<<512, 256, 0, stream>>>(tgt, ln1g, ln1b, qpos, nullptr, t21_bf, qk_bf);

  // q|k projection (N=512) and v projection (N=256)
  gemm_kernel<<<dim3(8, 8), 256, 0, stream>>>(qk_bf, inw_bf, inb, nullptr,
      qkp, nullptr, 512, 512, 256, 1.f, 0);
  gemm_kernel<<<dim3(8, 4), 256, 0, stream>>>(t21_bf, inw_bf + 512 * 256, inb + 512, nullptr,
      vp, nullptr, 512, 256, 256, 1.f, 0);

  attn_kernel<<<32, 256, 0, stream>>>(qkp, vp, ao_bf);

  // out-proj + residual tgt -> tgta
  gemm_kernel<<<dim3(8, 4), 256, 0, stream>>>(ao_bf, aow_bf, aob, tgt,
      tgta, nullptr, 512, 256, 256, 1.f, 0);

  // ln2 -> t22 (f32)
  ln_kernel<<<512, 256, 0, stream>>>(tgta, ln2g, ln2b, nullptr, t22_f, nullptr, nullptr);

  // relation: (x,y from rel) -> h ; h -> sim (in-place dump) ; y+sim -> weighted sum
  relpass_kernel<0><<<512, 1024, 0, stream>>>(rel, mem, t22_f, nullptr, w1pk, m1b,
      h_sw, y_sw, nullptr);
  relpass_kernel<1><<<512, 1024, 0, stream>>>(nullptr, nullptr, nullptr, h_sw, w2pk, m2b,
      h_sw, nullptr, nullptr);
  relpass_kernel<2><<<512, 1024, 0, stream>>>(nullptr, nullptr, nullptr, y_sw, wvpk, vb,
      trel_bf, nullptr, h_sw);

  // t = relu(t@o_w + o_b) + t22
  gemm_kernel<<<dim3(8, 4), 256, 0, stream>>>(trel_bf, ow_bf, ob, t22_f,
      tgtr, nullptr, 512, 256, 256, 1.f, 1);

  // ln3 -> bf16
  ln_kernel<<<512, 256, 0, stream>>>(tgtr, ln3g, ln3b, nullptr, nullptr, t23_bf, nullptr);

  // ffn
  gemm_kernel<<<dim3(8, 16), 256, 0, stream>>>(t23_bf, f1w_bf, f1b, nullptr,
      nullptr, ffh_bf, 512, 1024, 256, 1.f, 1);
  gemm_kernel<<<dim3(8, 4), 256, 0, stream>>>(ffh_bf, f2w_bf, f2b, tgtr,
      (float*)d_out, nullptr, 512, 256, 1024, 1.f, 0);
}

// Round 7
// 330.984 us; speedup vs baseline: 2.7644x; 1.1279x over previous
//
#include <hip/hip_runtime.h>
#include <hip/hip_bf16.h>
#include <cstdint>
#include <cstddef>

#define DEV __device__ __forceinline__

typedef __attribute__((ext_vector_type(8))) short short8;
typedef __attribute__((ext_vector_type(4))) float f32x4;

constexpr int Dm  = 256;
constexpr int Qn  = 128;
constexpr int Cn  = 512;
constexpr int Bn  = 4;

DEV unsigned short f2bf(float f){
  unsigned int u = __builtin_bit_cast(unsigned int, f);
  u += 0x7fffu + ((u >> 16) & 1u);
  return (unsigned short)(u >> 16);
}
DEV unsigned int pk2(float a, float b){
  return (unsigned int)f2bf(a) | ((unsigned int)f2bf(b) << 16);
}

DEV f32x4 mfma16(short8 a, short8 b, f32x4 c){
  return __builtin_amdgcn_mfma_f32_16x16x32_bf16(a, b, c, 0, 0, 0);
}

// 16x16x32 fragment load from XOR-swizzled LDS tile (rowbytes bytes/row) — for gemm_kernel
DEV short8 ldfrag(const unsigned short* buf, int rowbytes, int row0, int ks, int l){
  int r = row0 + (l & 15);
  int byte = (ks * 64 + ((l >> 4) * 16)) ^ ((r & 7) << 4);
  return *(const short8*)((const char*)buf + r * rowbytes + byte);
}

// async global->LDS, 16B/lane; LDS dest = wave-uniform base (HW adds lane*16)
DEV void gload_lds16(const void* g, void* lds){
  __builtin_amdgcn_global_load_lds(
      (const __attribute__((address_space(1))) unsigned int*)g,
      (__attribute__((address_space(3))) unsigned int*)lds, 16, 0, 0);
}

// ---------------------------------------------------------------- converts + weight packs
// pack W[f][d] into the fragment image: byte f*512 + ((d8*16) ^ ((f&15)<<4))
DEV void packw(unsigned short* dst, const float* src, int j){
  int f = j >> 8, d = j & 255;
  int d8 = d >> 3, e = d & 7;
  int byte = (d8 * 16) ^ ((f & 15) << 4);
  dst[f * 256 + (byte >> 1) + e] = f2bf(src[j]);
}

__global__ __launch_bounds__(256) void conv_all_kernel(
    const float* inw, unsigned short* inw_bf,
    const float* aow, unsigned short* aow_bf,
    const float* ow,  unsigned short* ow_bf,
    const float* f1w, unsigned short* f1w_bf,
    const float* f2w, unsigned short* f2w_bf,
    const float* m1w, unsigned short* w1pk,
    const float* m2w, unsigned short* w2pk,
    const float* vw,  unsigned short* wvpk)
{
  const int total = 196608 + 65536 + 65536 + 262144 + 262144 + 3 * 65536;
  for (int i = blockIdx.x * 256 + threadIdx.x; i < total; i += gridDim.x * 256){
    int j = i;
    if (j < 196608){ inw_bf[j] = f2bf(inw[j]); continue; } j -= 196608;
    if (j < 65536) { aow_bf[j] = f2bf(aow[j]); continue; } j -= 65536;
    if (j < 65536) { ow_bf[j]  = f2bf(ow[j]);  continue; } j -= 65536;
    if (j < 262144){ f1w_bf[j] = f2bf(f1w[j]); continue; } j -= 262144;
    if (j < 262144){ f2w_bf[j] = f2bf(f2w[j]); continue; } j -= 262144;
    if (j < 65536) { packw(w1pk, m1w, j); continue; } j -= 65536;
    if (j < 65536) { packw(w2pk, m2w, j); continue; } j -= 65536;
    packw(wvpk, vw, j);
  }
}

// ---------------------------------------------------------------- layernorm
__global__ __launch_bounds__(256) void ln_kernel(
    const float* __restrict__ in, const float* __restrict__ g, const float* __restrict__ bt,
    const float* __restrict__ addp,
    float* __restrict__ outF, unsigned short* __restrict__ outA, unsigned short* __restrict__ outB)
{
  const int r = blockIdx.x, t = threadIdx.x;
  float x = in[(size_t)r * 256 + t];
  float s = x, s2 = x * x;
  #pragma unroll
  for (int m = 1; m < 64; m <<= 1){ s += __shfl_xor(s, m, 64); s2 += __shfl_xor(s2, m, 64); }
  __shared__ float ls[8];
  int w = t >> 6, l = t & 63;
  if (l == 0){ ls[w] = s; ls[4 + w] = s2; }
  __syncthreads();
  s  = ls[0] + ls[1] + ls[2] + ls[3];
  s2 = ls[4] + ls[5] + ls[6] + ls[7];
  float mean = s * (1.f / 256.f);
  float var  = s2 * (1.f / 256.f) - mean * mean;
  float y = (x - mean) * rsqrtf(var + 1e-5f) * g[t] + bt[t];
  size_t o = (size_t)r * 256 + t;
  if (outF) outF[o] = y;
  if (outA) outA[o] = f2bf(y);
  if (outB) outB[o] = f2bf(y + addp[o]);
}

// ---------------------------------------------------------------- generic GEMM (small mats)
__global__ __launch_bounds__(256, 4) void gemm_kernel(
    const unsigned short* __restrict__ A, const unsigned short* __restrict__ W,
    const float* __restrict__ bias, const float* __restrict__ resid,
    float* __restrict__ Cf, unsigned short* __restrict__ Cb,
    int M, int N, int K, float alpha, int relu)
{
  __shared__ unsigned short As[64 * 64];
  __shared__ unsigned short Ws[64 * 64];
  const int tid = threadIdx.x;
  const int l = tid & 63;
  const int w = tid >> 6;
  const int wm = w >> 1, wn = w & 1;
  const int bm = blockIdx.x * 64, bn = blockIdx.y * 64;
  f32x4 acc[2][2] = {{{0,0,0,0},{0,0,0,0}},{{0,0,0,0},{0,0,0,0}}};

  for (int kc = 0; kc < K; kc += 64){
    __syncthreads();
    #pragma unroll
    for (int i = 0; i < 2; ++i){
      int idx = tid + i * 256;
      int r = idx >> 3, s = idx & 7;
      int byte = (s * 16) ^ ((r & 7) << 4);
      *(short8*)((char*)As + r * 128 + byte) = *(const short8*)(A + (size_t)(bm + r) * K + kc + s * 8);
      *(short8*)((char*)Ws + r * 128 + byte) = *(const short8*)(W + (size_t)(bn + r) * K + kc + s * 8);
    }
    __syncthreads();
    #pragma unroll
    for (int ks = 0; ks < 2; ++ks){
      short8 af[2], bf[2];
      af[0] = ldfrag(As, 128, wm * 32,      ks, l);
      af[1] = ldfrag(As, 128, wm * 32 + 16, ks, l);
      bf[0] = ldfrag(Ws, 128, wn * 32,      ks, l);
      bf[1] = ldfrag(Ws, 128, wn * 32 + 16, ks, l);
      #pragma unroll
      for (int i = 0; i < 2; ++i)
        #pragma unroll
        for (int j = 0; j < 2; ++j)
          acc[i][j] = mfma16(af[i], bf[j], acc[i][j]);
    }
  }
  #pragma unroll
  for (int i = 0; i < 2; ++i)
  #pragma unroll
  for (int j = 0; j < 2; ++j){
    int col = bn + wn * 32 + j * 16 + (l & 15);
    float bv = bias ? bias[col] : 0.f;
    #pragma unroll
    for (int u = 0; u < 4; ++u){
      int row = bm + wm * 32 + i * 16 + ((l >> 4) << 2) + u;
      float v = alpha * acc[i][j][u] + bv;
      if (relu) v = fmaxf(v, 0.f);
      if (resid) v += resid[(size_t)row * N + col];
      if (Cf) Cf[(size_t)row * N + col] = v;
      if (Cb) Cb[(size_t)row * N + col] = f2bf(v);
    }
  }
}

// ---------------------------------------------------------------- self-attention
__global__ __launch_bounds__(256) void attn_kernel(
    const float* __restrict__ qkp, const float* __restrict__ vp,
    unsigned short* __restrict__ attn_o)
{
  __shared__ float ks[128][33];
  __shared__ float vs[128][33];
  __shared__ float sc[128][129];
  const int bh = blockIdx.x;
  const int b = bh >> 3, h = bh & 7;
  const int tid = threadIdx.x;
  const int lrow = tid >> 1;
  const int half = tid & 1;
  {
    int s = tid >> 1;
    int d0 = half * 16;
    const float* kp = qkp + ((size_t)s * Bn + b) * 512 + 256 + h * 32 + d0;
    const float* vv = vp  + ((size_t)s * Bn + b) * 256 +       h * 32 + d0;
    #pragma unroll
    for (int d = 0; d < 16; d += 4){
      *(float4*)&ks[s][d0 + d] = *(const float4*)(kp + d);
      *(float4*)&vs[s][d0 + d] = *(const float4*)(vv + d);
    }
  }
  __syncthreads();
  float qv[32];
  const float* qp = qkp + ((size_t)lrow * Bn + b) * 512 + h * 32;
  #pragma unroll
  for (int d = 0; d < 32; ++d) qv[d] = qp[d];
  const float scale = 0.17677669529663687f;
  float mloc = -1e30f;
  for (int s2 = 0; s2 < 64; ++s2){
    int s = half * 64 + s2;
    float dot = 0.f;
    #pragma unroll
    for (int d = 0; d < 32; ++d) dot += qv[d] * ks[s][d];
    dot *= scale;
    sc[lrow][s] = dot;
    mloc = fmaxf(mloc, dot);
  }
  float m = fmaxf(mloc, __shfl_xor(mloc, 1, 64));
  float sum = 0.f;
  for (int s2 = 0; s2 < 64; ++s2){
    int s = half * 64 + s2;
    float e = __expf(sc[lrow][s] - m);
    sum += e;
    sc[lrow][s] = e;
  }
  sum += __shfl_xor(sum, 1, 64);
  float inv = 1.f / sum;
  float o[32];
  #pragma unroll
  for (int d = 0; d < 32; ++d) o[d] = 0.f;
  for (int s2 = 0; s2 < 64; ++s2){
    int s = half * 64 + s2;
    float e = sc[lrow][s];
    #pragma unroll
    for (int d = 0; d < 32; ++d) o[d] += e * vs[s][d];
  }
  #pragma unroll
  for (int d = 0; d < 32; ++d){
    o[d] += __shfl_xor(o[d], 1, 64);
    o[d] *= inv;
  }
  unsigned short* op = attn_o + ((size_t)lrow * Bn + b) * 256 + h * 32 + half * 16;
  #pragma unroll
  for (int d = 0; d < 16; ++d) op[d] = f2bf(o[half * 16 + d]);
}

// ---------------------------------------------------------------- fused relation branch
// One block per qb, 512 threads = 8 waves (wave w owns f-slice [w*32, w*32+32)).
// W1 LDS-resident; W2, Wv in registers (per-thread A-fragments, statically indexed).
// Per 16-c-row tile: x = t22-mem+rel, y = rel+mem -> LDS; h = relu(x@W1+b1) -> LDS;
// sim = (h@W2+b2)/16, v2 = y@Wv+vb; accumulate ta += exp(sim)*v2, la += exp(sim).
// Output trel[qb][f] = ta/la. Global traffic = rel read only.
__global__ __launch_bounds__(512, 2) void relfused_kernel(
    const float* __restrict__ rel, const float* __restrict__ memp,
    const float* __restrict__ t22f,
    const unsigned short* __restrict__ W1g,
    const unsigned short* __restrict__ W2g,
    const unsigned short* __restrict__ Wvg,
    const float* __restrict__ b1, const float* __restrict__ b2,
    const float* __restrict__ vbp,
    unsigned short* __restrict__ trel)
{
  __shared__ unsigned short W1t[65536];  // 128 KB
  __shared__ unsigned short xb[4096];    // 8 KB: 16 rows x 512 B, swizzled
  __shared__ unsigned short yb[4096];
  __shared__ unsigned short hb[4096];

  const int qb = blockIdx.x;
  const int q = qb >> 2, b = qb & 3;
  const int tid = threadIdx.x;
  const int w = tid >> 6, l = tid & 63;
  const int l15 = l & 15, lg = l >> 4;

  // ---- stage W1 -> LDS (async; dest wave-uniform, HW adds lane*16)
  #pragma unroll
  for (int i = 0; i < 16; ++i){
    int base = (w * 16 + i) * 64;
    gload_lds16((const char*)W1g + ((size_t)base + l) * 16, (char*)W1t + (size_t)base * 16);
  }

  // ---- W2, Wv A-fragments -> registers (64 VGPR each)
  short8 w2r[2][8], wvr[2][8];
  #pragma unroll
  for (int j = 0; j < 2; ++j){
    int f = w * 32 + j * 16 + l15;
    #pragma unroll
    for (int kc = 0; kc < 8; ++kc){
      int byte = f * 512 + ((kc * 64 + lg * 16) ^ ((f & 15) << 4));
      w2r[j][kc] = *(const short8*)((const char*)W2g + byte);
      wvr[j][kc] = *(const short8*)((const char*)Wvg + byte);
    }
  }

  // ---- biases for this thread's (f = w*32 + j*16 + lg*4 + u)
  float bv1[2][4], bv2[2][4], bvv[2][4];
  #pragma unroll
  for (int j = 0; j < 2; ++j)
    #pragma unroll
    for (int u = 0; u < 4; ++u){
      int f = w * 32 + j * 16 + lg * 4 + u;
      bv1[j][u] = b1[f]; bv2[j][u] = b2[f]; bvv[j][u] = vbp[f];
    }

  // ---- staging ids: thread stages row srow (of 16), d-chunk d8
  const int srow = tid >> 5, d8 = tid & 31;
  const int toff = srow * 512 + ((d8 * 16) ^ ((srow & 15) << 4));
  const float4 t20 = *(const float4*)(t22f + (size_t)qb * 256 + d8 * 8);
  const float4 t21 = *(const float4*)(t22f + (size_t)qb * 256 + d8 * 8 + 4);
  const float* relbase = rel + (((size_t)q * 512 + srow) * 4 + b) * 256 + d8 * 8;
  const float* membase = memp + ((size_t)(srow * 4 + b)) * 256 + d8 * 8;

  float4 r0 = *(const float4*)relbase;
  float4 r1 = *(const float4*)(relbase + 4);
  float4 m0 = *(const float4*)membase;
  float4 m1 = *(const float4*)(membase + 4);

  float ta[2][4], la[2][4];
  #pragma unroll
  for (int j = 0; j < 2; ++j)
    #pragma unroll
    for (int u = 0; u < 4; ++u){ ta[j][u] = 0.f; la[j][u] = 0.f; }

  for (int t = 0; t < 32; ++t){
    // ---- stage x, y tiles (regs hold tile t)
    uint4 xw, yw;
    xw.x = pk2(t20.x - m0.x + r0.x, t20.y - m0.y + r0.y);
    xw.y = pk2(t20.z - m0.z + r0.z, t20.w - m0.w + r0.w);
    xw.z = pk2(t21.x - m1.x + r1.x, t21.y - m1.y + r1.y);
    xw.w = pk2(t21.z - m1.z + r1.z, t21.w - m1.w + r1.w);
    yw.x = pk2(r0.x + m0.x, r0.y + m0.y);
    yw.y = pk2(r0.z + m0.z, r0.w + m0.w);
    yw.z = pk2(r1.x + m1.x, r1.y + m1.y);
    yw.w = pk2(r1.z + m1.z, r1.w + m1.w);
    *(uint4*)((char*)xb + toff) = xw;
    *(uint4*)((char*)yb + toff) = yw;
    // prefetch tile t+1 (hides under this tile's MFMAs)
    if (t < 31){
      const float* rp = relbase + (size_t)(t + 1) * 16384;
      const float* mp = membase + (size_t)(t + 1) * 16384;
      r0 = *(const float4*)rp;  r1 = *(const float4*)(rp + 4);
      m0 = *(const float4*)mp;  m1 = *(const float4*)(mp + 4);
    }
    if (t == 0) asm volatile("s_waitcnt vmcnt(0)" ::: "memory");  // W1 staged
    __syncthreads();   // xb, yb ready

    // ---- h GEMM (W1 from LDS)
    f32x4 acch[2] = {{0,0,0,0},{0,0,0,0}};
    #pragma unroll
    for (int kc = 0; kc < 8; ++kc){
      short8 bx = *(const short8*)((const char*)xb + l15 * 512 + ((kc * 64 + lg * 16) ^ (l15 << 4)));
      #pragma unroll
      for (int j = 0; j < 2; ++j){
        int f = w * 32 + j * 16 + l15;
        short8 aw = *(const short8*)((const char*)W1t + f * 512 + ((kc * 64 + lg * 16) ^ ((f & 15) << 4)));
        acch[j] = mfma16(aw, bx, acch[j]);
      }
    }
    // h -> hb (bf16, same swizzled row layout; row = c = l15, byte base = f'*2)
    #pragma unroll
    for (int j = 0; j < 2; ++j){
      uint2 hp;
      hp.x = pk2(fmaxf(acch[j][0] + bv1[j][0], 0.f), fmaxf(acch[j][1] + bv1[j][1], 0.f));
      hp.y = pk2(fmaxf(acch[j][2] + bv1[j][2], 0.f), fmaxf(acch[j][3] + bv1[j][3], 0.f));
      int inrow = (w * 64 + j * 32 + lg * 8) ^ (l15 << 4);
      *(uint2*)((char*)hb + l15 * 512 + inrow) = hp;
    }
    __syncthreads();   // hb ready

    // ---- sim GEMM (W2 regs, h from LDS) + v2 GEMM (Wv regs, y from LDS)
    f32x4 accs[2] = {{0,0,0,0},{0,0,0,0}};
    f32x4 accv[2] = {{0,0,0,0},{0,0,0,0}};
    #pragma unroll
    for (int kc = 0; kc < 8; ++kc){
      int inb = (kc * 64 + lg * 16) ^ (l15 << 4);
      short8 bh = *(const short8*)((const char*)hb + l15 * 512 + inb);
      short8 by = *(const short8*)((const char*)yb + l15 * 512 + inb);
      #pragma unroll
      for (int j = 0; j < 2; ++j){
        accs[j] = mfma16(w2r[j][kc], bh, accs[j]);
        accv[j] = mfma16(wvr[j][kc], by, accv[j]);
      }
    }
    #pragma unroll
    for (int j = 0; j < 2; ++j)
      #pragma unroll
      for (int u = 0; u < 4; ++u){
        float e = __expf((accs[j][u] + bv2[j][u]) * 0.0625f);
        float v2 = accv[j][u] + bvv[j][u];
        ta[j][u] += e * v2;
        la[j][u] += e;
      }
    if (t < 31) __syncthreads();   // phase-2 LDS reads done; next staging may overwrite
  }

  // ---- reduce over c-lanes (l15) and write trel
  #pragma unroll
  for (int j = 0; j < 2; ++j)
    #pragma unroll
    for (int u = 0; u < 4; ++u){
      #pragma unroll
      for (int m = 1; m <= 8; m <<= 1){
        ta[j][u] += __shfl_xor(ta[j][u], m, 64);
        la[j][u] += __shfl_xor(la[j][u], m, 64);
      }
    }
  if (l15 == 0){
    #pragma unroll
    for (int j = 0; j < 2; ++j){
      uint2 o;
      o.x = pk2(ta[j][0] / la[j][0], ta[j][1] / la[j][1]);
      o.y = pk2(ta[j][2] / la[j][2], ta[j][3] / la[j][3]);
      *(uint2*)(trel + (size_t)qb * 256 + w * 32 + j * 16 + lg * 4) = o;
    }
  }
}

// ---------------------------------------------------------------- launch
extern "C" void kernel_launch(void* const* d_in, const int* in_sizes, int n_in,
                              void* d_out, int out_size, void* d_ws, size_t ws_size,
                              hipStream_t stream)
{
  const float* tgt  = (const float*)d_in[0];
  const float* mem  = (const float*)d_in[1];
  const float* qpos = (const float*)d_in[2];
  const float* rel  = (const float*)d_in[3];
  const float* ln1g = (const float*)d_in[4];
  const float* ln1b = (const float*)d_in[5];
  const float* ln2g = (const float*)d_in[6];
  const float* ln2b = (const float*)d_in[7];
  const float* ln3g = (const float*)d_in[8];
  const float* ln3b = (const float*)d_in[9];
  const float* inw  = (const float*)d_in[10];
  const float* inb  = (const float*)d_in[11];
  const float* aow  = (const float*)d_in[12];
  const float* aob  = (const float*)d_in[13];
  const float* m1w  = (const float*)d_in[14];
  const float* m1b  = (const float*)d_in[15];
  const float* m2w  = (const float*)d_in[16];
  const float* m2b  = (const float*)d_in[17];
  const float* vw   = (const float*)d_in[18];
  const float* vb   = (const float*)d_in[19];
  const float* ow   = (const float*)d_in[20];
  const float* ob   = (const float*)d_in[21];
  const float* f1w  = (const float*)d_in[22];
  const float* f1b  = (const float*)d_in[23];
  const float* f2w  = (const float*)d_in[24];
  const float* f2b  = (const float*)d_in[25];

  char* ws = (char*)d_ws;
  size_t off = 0;
  auto alloc = [&](size_t bytes) -> char* {
    char* p = ws + off; off += (bytes + 255) & ~size_t(255); return p;
  };
  unsigned short* w1pk    = (unsigned short*)alloc(256 * 256 * 2);
  unsigned short* w2pk    = (unsigned short*)alloc(256 * 256 * 2);
  unsigned short* wvpk    = (unsigned short*)alloc(256 * 256 * 2);
  unsigned short* inw_bf  = (unsigned short*)alloc(768 * 256 * 2);
  unsigned short* aow_bf  = (unsigned short*)alloc(256 * 256 * 2);
  unsigned short* ow_bf   = (unsigned short*)alloc(256 * 256 * 2);
  unsigned short* f1w_bf  = (unsigned short*)alloc(1024 * 256 * 2);
  unsigned short* f2w_bf  = (unsigned short*)alloc(256 * 1024 * 2);
  unsigned short* t21_bf  = (unsigned short*)alloc(512 * 256 * 2);
  unsigned short* qk_bf   = (unsigned short*)alloc(512 * 256 * 2);
  float*          qkp     = (float*)alloc(512 * 512 * 4);
  float*          vp      = (float*)alloc(512 * 256 * 4);
  unsigned short* ao_bf   = (unsigned short*)alloc(512 * 256 * 2);
  float*          tgta    = (float*)alloc(512 * 256 * 4);
  float*          t22_f   = (float*)alloc(512 * 256 * 4);
  unsigned short* trel_bf = (unsigned short*)alloc(512 * 256 * 2);
  float*          tgtr    = (float*)alloc(512 * 256 * 4);
  unsigned short* t23_bf  = (unsigned short*)alloc(512 * 256 * 2);
  unsigned short* ffh_bf  = (unsigned short*)alloc(512 * 1024 * 2);

  conv_all_kernel<<<2048, 256, 0, stream>>>(inw, inw_bf, aow, aow_bf, ow, ow_bf,
      f1w, f1w_bf, f2w, f2w_bf, m1w, w1pk, m2w, w2pk, vw, wvpk);

  // ln1 -> tgt2_1 (bf16), qk = tgt2_1 + query_pos (bf16)
  ln_kernel<<<512, 256, 0, stream>>>(tgt, ln1g, ln1b, qpos, nullptr, t21_bf, qk_bf);

  // q|k projection (N=512) and v projection (N=256)
  gemm_kernel<<<dim3(8, 8), 256, 0, stream>>>(qk_bf, inw_bf, inb, nullptr,
      qkp, nullptr, 512, 512, 256, 1.f, 0);
  gemm_kernel<<<dim3(8, 4), 256, 0, stream>>>(t21_bf, inw_bf + 512 * 256, inb + 512, nullptr,
      vp, nullptr, 512, 256, 256, 1.f, 0);

  attn_kernel<<<32, 256, 0, stream>>>(qkp, vp, ao_bf);

  // out-proj + residual tgt -> tgta
  gemm_kernel<<<dim3(8, 4), 256, 0, stream>>>(ao_bf, aow_bf, aob, tgt,
      tgta, nullptr, 512, 256, 256, 1.f, 0);

  // ln2 -> t22 (f32)
  ln_kernel<<<512, 256, 0, stream>>>(tgta, ln2g, ln2b, nullptr, t22_f, nullptr, nullptr);

  // fused relation branch
  relfused_kernel<<<512, 512, 0, stream>>>(rel, mem, t22_f, w1pk, w2pk, wvpk,
      m1b, m2b, vb, trel_bf);

  // t = relu(t@o_w + o_b) + t22
  gemm_kernel<<<dim3(8, 4), 256, 0, stream>>>(trel_bf, ow_bf, ob, t22_f,
      tgtr, nullptr, 512, 256, 256, 1.f, 1);

  // ln3 -> bf16
  ln_kernel<<<512, 256, 0, stream>>>(tgtr, ln3g, ln3b, nullptr, nullptr, t23_bf, nullptr);

  // ffn
  gemm_kernel<<<dim3(8, 16), 256, 0, stream>>>(t23_bf, f1w_bf, f1b, nullptr,
      nullptr, ffh_bf, 512, 1024, 256, 1.f, 1);
  gemm_kernel<<<dim3(8, 4), 256, 0, stream>>>(ffh_bf, f2w_bf, f2b, tgtr,
      (float*)d_out, nullptr, 512, 256, 1024, 1.f, 0);
}